// Round 1
// 525.092 us; speedup vs baseline: 1.0499x; 1.0499x over previous
//
#include <hip/hip_runtime.h>
#include <hip/hip_fp16.h>
#include <cstdint>
#include <cstddef>

#define B_ 2
#define C_ 64
#define H_ 256
#define W_ 256
#define HW_ (H_*W_)
#define DG_ 8
#define CG_ 8
#define KK_ 9
#define NOFF_ 144
#define NMSK_ 72
#define NTOT_ 216
#define KRED_ 1152   // 128 * 9
#define XPH_ 258     // padded spatial dim (H+2)

typedef __bf16 bf16x8 __attribute__((ext_vector_type(8)));
typedef short  short8 __attribute__((ext_vector_type(8)));
typedef float  f32x4  __attribute__((ext_vector_type(4)));

__device__ __forceinline__ short f2bf(float f) {
    union { float f; uint32_t u; } a; a.f = f;
    uint32_t u = a.u;
    uint32_t r = (u + 0x7fffu + ((u >> 16) & 1u)) >> 16;
    return (short)r;
}

// async global->LDS, 16B per lane: dest = wave-uniform base + lane*16
typedef __attribute__((address_space(1))) const unsigned int g_u32;
typedef __attribute__((address_space(3))) unsigned int l_u32;
__device__ __forceinline__ void gl_lds16(const void* g, void* l) {
    __builtin_amdgcn_global_load_lds((g_u32*)g, (l_u32*)l, 16, 0, 0);
}

// ---------------- kernel 0a: weight transpose (fp32, for apply) ----------------
__global__ void wtrans_kernel(const float* __restrict__ w, float* __restrict__ wT) {
    int idx = blockIdx.x * 256 + threadIdx.x;   // 36864 = 576*64
    int ck = idx >> 6;
    int o  = idx & 63;
    wT[idx] = w[o * 576 + ck];
}

// ------- kernel 0b: conv weights -> bf16, tap-major K, padded to 256 rows ------
__global__ void wtrans2_kernel(const float* __restrict__ off_w,
                               const float* __restrict__ msk_w,
                               short* __restrict__ Bw) {
    int idx = blockIdx.x * 256 + threadIdx.x;   // 256*1152 = 294912
    int n = idx / KRED_;
    int k = idx - n * KRED_;
    int r = k >> 7;           // tap 0..8
    int c = k & 127;          // channel 0..127
    float v = 0.f;
    if (n < NOFF_)      v = off_w[(size_t)n * KRED_ + c * 9 + r];
    else if (n < NTOT_) v = msk_w[(size_t)(n - NOFF_) * KRED_ + c * 9 + r];
    Bw[idx] = f2bf(v);
}

// ---------------- kernel 0c: out = bias (for atomic accumulation) ---------------
__global__ void init_out(const float* __restrict__ bias, float* __restrict__ out) {
    int i = blockIdx.x * 256 + threadIdx.x;   // 2097152 float4s
    int ch = (i >> 14) & 63;
    float bv = bias[ch];
    ((float4*)out)[i] = make_float4(bv, bv, bv, bv);
}

// ---------------- kernel 0d: zero the padded NHWC bf16 buffer -------------------
__global__ void zero_xp(float4* __restrict__ xp, unsigned n16) {
    unsigned i = blockIdx.x * 256 + threadIdx.x;
    if (i < n16) xp[i] = make_float4(0.f, 0.f, 0.f, 0.f);
}

// ---------------- kernel 0e: pack concat(ref,nbr) -> padded NHWC bf16 -----------
// xp[b][y][x][c], y/x in [0,258) representing -1..256, zero border; c in [0,128)
__global__ void pack_xp(const float* __restrict__ ref,
                        const float* __restrict__ nbr,
                        short* __restrict__ xp) {
    const int by = blockIdx.x;          // b*256 + h
    const int b = by >> 8;
    const int h = by & 255;
    const int x = threadIdx.x;
    const float* s0 = ref + (size_t)b * 64 * HW_ + (size_t)h * W_ + x;
    const float* s1 = nbr + (size_t)b * 64 * HW_ + (size_t)h * W_ + x;
    short* dst = xp + ((size_t)(b * XPH_ + h + 1) * XPH_ + (x + 1)) * 128;
    #pragma unroll
    for (int cc = 0; cc < 16; ++cc) {
        const float* src = (cc < 8 ? s0 : s1) + (size_t)((cc & 7) * 8) * HW_;
        short8 o;
        #pragma unroll
        for (int j = 0; j < 8; ++j) o[j] = f2bf(src[(size_t)j * HW_]);
        *reinterpret_cast<short8*>(dst + cc * 8) = o;
    }
}

// ---------------- kernel 1: offset/mask conv — bf16 MFMA implicit GEMM ----------
// A staged from padded NHWC bf16 via global_load_lds (4 async issues/thread/iter)
__global__ __launch_bounds__(256) void conv_mfma(
    const short* __restrict__ xp, const short* __restrict__ Bw,
    const float* __restrict__ off_b, const float* __restrict__ msk_b,
    __half* __restrict__ off_o, __half* __restrict__ msk_o)
{
    __shared__ __align__(16) short As[4][128][8];   // [quad][m][j]  k = quad*8+j
    __shared__ __align__(16) short Bs[4][128][8];   // [quad][n][j]

    const int tid  = threadIdx.x;
    const int lane = tid & 63;
    const int wid  = tid >> 6;
    const int wm   = wid & 1;
    const int wn   = wid >> 1;

    const int m0 = blockIdx.x * 128;
    const int b  = m0 >> 16;
    const int h  = (m0 >> 8) & 255;
    const int w0 = m0 & 255;
    const int nbase = blockIdx.y * 128;

    const int col     = lane & 15;
    const int rowbase = (lane >> 4) * 4;
    const int quad    = lane >> 4;

    const short* xpb = xp + (size_t)b * ((size_t)XPH_ * XPH_ * 128);
    const short* BwB = Bw + (size_t)(nbase + lane) * KRED_ + wid * 8;

    f32x4 acc[4][4];
    #pragma unroll
    for (int i = 0; i < 4; ++i)
        #pragma unroll
        for (int j = 0; j < 4; ++j) acc[i][j] = f32x4{0.f, 0.f, 0.f, 0.f};

    #pragma unroll 1
    for (int kc = 0; kc < 36; ++kc) {
        const int r  = kc >> 2;           // tap 0..8
        const int c0 = (kc & 3) * 32;     // channel chunk
        const int dy = r / 3;
        const int dx = r - dy * 3;

        // A: wave wid stages quad wid (channels c0+wid*8 .. +8) for 128 pixels
        const short* srcA = xpb + ((size_t)(h + dy) * XPH_ + (w0 + dx)) * 128
                            + c0 + wid * 8;
        gl_lds16(srcA + (size_t)lane * 128,        &As[wid][0][0]);
        gl_lds16(srcA + (size_t)(64 + lane) * 128, &As[wid][64][0]);

        // B: wave wid stages quad wid for 128 n-rows
        const short* srcB = BwB + kc * 32;
        gl_lds16(srcB,                      &Bs[wid][0][0]);
        gl_lds16(srcB + (size_t)64 * KRED_, &Bs[wid][64][0]);

        __syncthreads();

        bf16x8 af[4], bfv[4];
        #pragma unroll
        for (int mt = 0; mt < 4; ++mt)
            af[mt] = *reinterpret_cast<const bf16x8*>(&As[quad][wm * 64 + mt * 16 + col][0]);
        #pragma unroll
        for (int nt = 0; nt < 4; ++nt)
            bfv[nt] = *reinterpret_cast<const bf16x8*>(&Bs[quad][wn * 64 + nt * 16 + col][0]);
        #pragma unroll
        for (int mt = 0; mt < 4; ++mt)
            #pragma unroll
            for (int nt = 0; nt < 4; ++nt)
                acc[mt][nt] = __builtin_amdgcn_mfma_f32_16x16x32_bf16(
                    af[mt], bfv[nt], acc[mt][nt], 0, 0, 0);
        __syncthreads();
    }

    #pragma unroll
    for (int mt = 0; mt < 4; ++mt) {
        const int wloc = w0 + wm * 64 + mt * 16 + rowbase;
        #pragma unroll
        for (int nt = 0; nt < 4; ++nt) {
            const int n = nbase + wn * 64 + nt * 16 + col;
            if (n >= NTOT_) continue;
            const bool is_off = (n < NOFF_);
            const float bia = is_off ? off_b[n] : msk_b[n - NOFF_];
            union { uint2 u; __half hx[4]; } pk;
            #pragma unroll
            for (int rr = 0; rr < 4; ++rr) {
                float v = acc[mt][nt][rr] + bia;
                if (!is_off) v = 1.f / (1.f + __expf(-v));
                pk.hx[rr] = __float2half(v);
            }
            __half* dst = is_off
                ? (off_o + ((size_t)(b * NOFF_ + n) * H_ + h) * W_ + wloc)
                : (msk_o + ((size_t)(b * NMSK_ + (n - NOFF_)) * H_ + h) * W_ + wloc);
            *(uint2*)dst = pk.u;
        }
    }
}

// ---------------- kernel 2: bilinear sample + modulated einsum (group-split) ----
// weights read via wave-uniform global loads (scalar-cache path, no LDS)
__global__ __launch_bounds__(256) void apply_partial(
    const float* __restrict__ nbr, const __half* __restrict__ off_o,
    const __half* __restrict__ msk_o, const float* __restrict__ wT,
    float* __restrict__ out)
{
    const int tid = threadIdx.x;
    const int bh = blockIdx.x;
    const int b = bh >> 8;
    const int h = bh & 255;
    const int w = tid;
    const int g0 = blockIdx.y * 2;

    float4 acc[16];
    #pragma unroll
    for (int j = 0; j < 16; ++j) acc[j] = make_float4(0.f, 0.f, 0.f, 0.f);

    const int pix = h * W_ + w;

    for (int gi = 0; gi < 2; ++gi) {
        const int g = g0 + gi;
        const float*  nbg  = nbr   + ((size_t)b * C_ + g * CG_) * HW_;
        const __half* offp = off_o + ((size_t)(b * NOFF_ + g * 18)) * HW_ + pix;
        const __half* mskp = msk_o + ((size_t)(b * NMSK_ + g * 9)) * HW_ + pix;
        const float*  wg   = wT + (size_t)g * (CG_ * KK_ * 64);

        // prefetch all 27 offset/mask values (independent loads, overlap latency)
        float dyv[9], dxv[9], mmv[9];
        #pragma unroll
        for (int k = 0; k < 9; ++k) {
            dyv[k] = __half2float(offp[(size_t)(2*k)     * HW_]);
            dxv[k] = __half2float(offp[(size_t)(2*k + 1) * HW_]);
            mmv[k] = __half2float(mskp[(size_t)k * HW_]);
        }

        #pragma unroll 1
        for (int k = 0; k < 9; ++k) {
            float ys = (float)(h - 1 + k / 3) + dyv[k];
            float xs = (float)(w - 1 + k % 3) + dxv[k];
            float mm = mmv[k];
            float y0f = floorf(ys), x0f = floorf(xs);
            float wy = ys - y0f, wx = xs - x0f;
            int y0 = (int)y0f, x0 = (int)x0f;
            int y1 = y0 + 1, x1 = x0 + 1;
            int yc0 = min(max(y0, 0), H_-1), yc1 = min(max(y1, 0), H_-1);
            float wy0v = (1.f - wy) * (((unsigned)y0 < H_) ? mm : 0.f);
            float wy1v = wy * (((unsigned)y1 < H_) ? mm : 0.f);
            int xb = min(max(x0, 0), W_-2);
            float wx0v = (((unsigned)x0 < W_) ? (1.f - wx) : 0.f);
            float wx1v = (((unsigned)x1 < W_) ? wx : 0.f);
            float sx0 = (x0 == xb) ? wx0v : ((x1 == xb) ? wx1v : 0.f);
            float sx1 = (x1 == xb + 1) ? wx1v : ((x0 == xb + 1) ? wx0v : 0.f);
            int o0 = yc0 * W_ + xb, o1 = yc1 * W_ + xb;
            #pragma unroll
            for (int c = 0; c < CG_; ++c) {
                const float* pch = nbg + (size_t)c * HW_;
                float2 r0 = *(const float2*)(pch + o0);
                float2 r1 = *(const float2*)(pch + o1);
                float v = wy0v * (sx0 * r0.x + sx1 * r0.y)
                        + wy1v * (sx0 * r1.x + sx1 * r1.y);
                // wave-uniform address -> s_load through scalar cache
                const float* wp = wg + (c * 9 + k) * 64;
                #pragma unroll
                for (int j = 0; j < 16; ++j) {
                    float4 wv = *(const float4*)(wp + 4*j);
                    acc[j].x += v * wv.x;
                    acc[j].y += v * wv.y;
                    acc[j].z += v * wv.z;
                    acc[j].w += v * wv.w;
                }
            }
        }
    }

    float* op = out + (size_t)b * C_ * HW_ + pix;
    #pragma unroll
    for (int j = 0; j < 16; ++j) {
        atomicAdd(op + (size_t)(4*j+0)*HW_, acc[j].x);
        atomicAdd(op + (size_t)(4*j+1)*HW_, acc[j].y);
        atomicAdd(op + (size_t)(4*j+2)*HW_, acc[j].z);
        atomicAdd(op + (size_t)(4*j+3)*HW_, acc[j].w);
    }
}

extern "C" void kernel_launch(void* const* d_in, const int* in_sizes, int n_in,
                              void* d_out, int out_size, void* d_ws, size_t ws_size,
                              hipStream_t stream) {
    const float* ref    = (const float*)d_in[0];
    const float* nbr    = (const float*)d_in[1];
    const float* off_w  = (const float*)d_in[2];
    const float* off_b  = (const float*)d_in[3];
    const float* msk_w  = (const float*)d_in[4];
    const float* msk_b  = (const float*)d_in[5];
    const float* weight = (const float*)d_in[6];
    const float* bias   = (const float*)d_in[7];
    float* out = (float*)d_out;

    // ws carve: wT fp32 | off f16 | msk f16 | Bw bf16 (256 rows) | xp bf16 NHWC
    const size_t sz_wT  = (size_t)64 * 576 * 4;              // 147456
    const size_t sz_off = (size_t)B_ * NOFF_ * HW_ * 2;      // 37748736
    const size_t sz_msk = (size_t)B_ * NMSK_ * HW_ * 2;      // 18874368
    const size_t sz_Bw  = (size_t)256 * KRED_ * 2;           // 589824

    char* ws = (char*)d_ws;
    float*  wT    = (float*)ws;
    __half* off_o = (__half*)(ws + sz_wT);
    __half* msk_o = (__half*)(ws + sz_wT + sz_off);
    short*  Bw    = (short*)(ws + sz_wT + sz_off + sz_msk);
    short*  xp    = (short*)(ws + sz_wT + sz_off + sz_msk + sz_Bw);

    const size_t xp_shorts = (size_t)B_ * XPH_ * XPH_ * 128; // 17040384
    const unsigned n16 = (unsigned)(xp_shorts / 8);          // 16B chunks
    const int zgrid = (int)((n16 + 255) / 256);

    wtrans_kernel<<<144, 256, 0, stream>>>(weight, wT);
    wtrans2_kernel<<<1152, 256, 0, stream>>>(off_w, msk_w, Bw);
    zero_xp<<<zgrid, 256, 0, stream>>>((float4*)xp, n16);
    pack_xp<<<B_ * H_, 256, 0, stream>>>(ref, nbr, xp);
    init_out<<<8192, 256, 0, stream>>>(bias, out);
    conv_mfma<<<dim3(1024, 2), 256, 0, stream>>>(xp, Bw, off_b, msk_b,
                                                 off_o, msk_o);
    apply_partial<<<dim3(B_ * H_, 4), 256, 0, stream>>>(nbr, off_o, msk_o, wT, out);
}

// Round 2
// 399.716 us; speedup vs baseline: 1.3792x; 1.3137x over previous
//
#include <hip/hip_runtime.h>
#include <hip/hip_fp16.h>
#include <cstdint>
#include <cstddef>

#define B_ 2
#define C_ 64
#define H_ 256
#define W_ 256
#define HW_ (H_*W_)
#define DG_ 8
#define CG_ 8
#define KK_ 9
#define NOFF_ 144
#define NMSK_ 72
#define NTOT_ 216
#define KRED_ 1152   // 128 * 9
#define XPH_ 258     // padded spatial dim (H+2)

typedef __bf16 bf16x8 __attribute__((ext_vector_type(8)));
typedef short  short8 __attribute__((ext_vector_type(8)));
typedef float  f32x4  __attribute__((ext_vector_type(4)));

__device__ __forceinline__ short f2bf(float f) {
    union { float f; uint32_t u; } a; a.f = f;
    uint32_t u = a.u;
    uint32_t r = (u + 0x7fffu + ((u >> 16) & 1u)) >> 16;
    return (short)r;
}

// async global->LDS, 16B per lane: dest = wave-uniform base + lane*16
typedef __attribute__((address_space(1))) const unsigned int g_u32;
typedef __attribute__((address_space(3))) unsigned int l_u32;
__device__ __forceinline__ void gl_lds16(const void* g, void* l) {
    __builtin_amdgcn_global_load_lds((g_u32*)g, (l_u32*)l, 16, 0, 0);
}

// ---------------- kernel 0a: weight transpose (fp32, for apply) ----------------
__global__ void wtrans_kernel(const float* __restrict__ w, float* __restrict__ wT) {
    int idx = blockIdx.x * 256 + threadIdx.x;   // 36864 = 576*64
    int ck = idx >> 6;
    int o  = idx & 63;
    wT[idx] = w[o * 576 + ck];
}

// ------ kernel 0b: conv weights -> bf16, step-major, slot-swizzled, 256 rows ----
// Bw2[s][n][slot][8ch], s = c4*9 + tap; stored slot = q ^ ((n>>1)&3)
__global__ void wtrans2_kernel(const float* __restrict__ off_w,
                               const float* __restrict__ msk_w,
                               short* __restrict__ Bw) {
    int idx = blockIdx.x * 256 + threadIdx.x;   // 36*256*32 = 294912
    int s    = idx >> 13;          // 8192 shorts per step
    int rem  = idx & 8191;
    int n    = rem >> 5;
    int slot = (rem >> 3) & 3;
    int j    = rem & 7;
    int q    = slot ^ ((n >> 1) & 3);
    int c4   = s / 9;
    int tap  = s - c4 * 9;
    int ch   = c4 * 32 + q * 8 + j;
    float v = 0.f;
    if (n < NOFF_)      v = off_w[(size_t)n * KRED_ + ch * 9 + tap];
    else if (n < NTOT_) v = msk_w[(size_t)(n - NOFF_) * KRED_ + ch * 9 + tap];
    Bw[idx] = f2bf(v);
}

// ---------------- kernel 0c: out = bias (for atomic accumulation) ---------------
__global__ void init_out(const float* __restrict__ bias, float* __restrict__ out) {
    int i = blockIdx.x * 256 + threadIdx.x;   // 2097152 float4s
    int ch = (i >> 14) & 63;
    float bv = bias[ch];
    ((float4*)out)[i] = make_float4(bv, bv, bv, bv);
}

// ------- kernel 0e: pack concat(ref,nbr) -> chunk-planar padded bf16 ------------
// xp[b][c4][yi 258][xi 258][slot 4][8ch]; stored slot = q ^ ((xi>>1)&3); zero pad
__global__ void pack_xp2(const float* __restrict__ ref,
                         const float* __restrict__ nbr,
                         short* __restrict__ xp) {
    const int by = blockIdx.x;          // b*258 + yi
    const int b  = by / XPH_;
    const int yi = by - b * XPH_;
    const int c4 = blockIdx.y;
    const int yg = yi - 1;
    const float* base = (c4 < 2 ? ref : nbr) + ((size_t)b * 64 + (c4 & 1) * 32) * HW_;
    short* rowbase = xp + (((size_t)(b * 4 + c4) * XPH_ + yi) * XPH_) * 32;
    for (int xi = threadIdx.x; xi < XPH_; xi += 256) {
        const int xg = xi - 1;
        const bool valid = ((unsigned)yg < H_) && ((unsigned)xg < W_);
        short* dst = rowbase + (size_t)xi * 32;
        const int sig = (xi >> 1) & 3;
        #pragma unroll
        for (int q = 0; q < 4; ++q) {
            short8 o;
            if (valid) {
                const float* p = base + (size_t)(q * 8) * HW_ + (size_t)yg * W_ + xg;
                #pragma unroll
                for (int j = 0; j < 8; ++j) o[j] = f2bf(p[(size_t)j * HW_]);
            } else {
                #pragma unroll
                for (int j = 0; j < 8; ++j) o[j] = 0;
            }
            *reinterpret_cast<short8*>(dst + ((q ^ sig) * 8)) = o;
        }
    }
}

// ---------------- kernel 1: offset/mask conv — bf16 MFMA implicit GEMM ----------
// BM=128 px, BN=256 (all outputs, no y-split), BK=32; coalesced gl_lds staging
__global__ __launch_bounds__(256, 2) void conv_mfma(
    const short* __restrict__ xp, const short* __restrict__ Bw,
    const float* __restrict__ off_b, const float* __restrict__ msk_b,
    __half* __restrict__ off_o, __half* __restrict__ msk_o)
{
    __shared__ __align__(16) short As[128 * 32];   // [px][slot][8]  8 KB
    __shared__ __align__(16) short Bs[256 * 32];   // [n][slot][8]  16 KB

    const int tid  = threadIdx.x;
    const int lane = tid & 63;
    const int wid  = tid >> 6;
    const int wm   = wid & 1;
    const int wn   = wid >> 1;
    const int col     = lane & 15;
    const int quad    = lane >> 4;
    const int rowbase = quad * 4;

    // XCD-aware bijective swizzle (1024 blocks % 8 == 0)
    const int bid = blockIdx.x;
    const int wg  = (bid & 7) * 128 + (bid >> 3);
    const int m0 = wg << 7;
    const int b  = m0 >> 16;
    const int h  = (m0 >> 8) & 255;
    const int w0 = m0 & 255;

    // hoisted B fragment offsets (shorts)
    int bOff[8];
    #pragma unroll
    for (int nt = 0; nt < 8; ++nt) {
        int n = wn * 128 + nt * 16 + col;
        bOff[nt] = (n * 4 + (quad ^ ((n >> 1) & 3))) * 8;
    }
    int pxv[4];
    #pragma unroll
    for (int mt = 0; mt < 4; ++mt) pxv[mt] = wm * 64 + mt * 16 + col;

    f32x4 acc[4][8];
    #pragma unroll
    for (int i = 0; i < 4; ++i)
        #pragma unroll
        for (int j = 0; j < 8; ++j) acc[i][j] = f32x4{0.f, 0.f, 0.f, 0.f};

    int c4 = 0, dy = 0, dx = 0;
    #pragma unroll 1
    for (int s = 0; s < 36; ++s) {
        // A: contiguous 8 KB window [px 128][32ch] at (c4, h+dy, w0+dx)
        const short* sA = xp + ((((size_t)(b * 4 + c4) * XPH_ + (h + dy)) * XPH_
                                 + (w0 + dx)) << 5);
        gl_lds16(sA + (size_t)tid * 8,         As + (wid * 64) * 8);
        gl_lds16(sA + (size_t)(256 + tid) * 8, As + (256 + wid * 64) * 8);

        // B: contiguous 16 KB step slice (L2-resident)
        const short* sB = Bw + ((size_t)s << 13);
        #pragma unroll
        for (int i = 0; i < 4; ++i)
            gl_lds16(sB + (size_t)(i * 256 + tid) * 8, Bs + (i * 256 + wid * 64) * 8);

        __syncthreads();

        bf16x8 af[4], bv[8];
        #pragma unroll
        for (int mt = 0; mt < 4; ++mt) {
            const int px = pxv[mt];
            const int slot = quad ^ (((dx + px) >> 1) & 3);
            af[mt] = *reinterpret_cast<const bf16x8*>(&As[(px * 4 + slot) * 8]);
        }
        #pragma unroll
        for (int nt = 0; nt < 8; ++nt)
            bv[nt] = *reinterpret_cast<const bf16x8*>(&Bs[bOff[nt]]);

        #pragma unroll
        for (int mt = 0; mt < 4; ++mt)
            #pragma unroll
            for (int nt = 0; nt < 8; ++nt)
                acc[mt][nt] = __builtin_amdgcn_mfma_f32_16x16x32_bf16(
                    af[mt], bv[nt], acc[mt][nt], 0, 0, 0);

        __syncthreads();

        if (++dx == 3) { dx = 0; if (++dy == 3) { dy = 0; ++c4; } }
    }

    #pragma unroll
    for (int mt = 0; mt < 4; ++mt) {
        const int wloc = w0 + wm * 64 + mt * 16 + rowbase;
        #pragma unroll
        for (int nt = 0; nt < 8; ++nt) {
            const int n = wn * 128 + nt * 16 + col;
            if (n >= NTOT_) continue;
            const bool is_off = (n < NOFF_);
            const float bia = is_off ? off_b[n] : msk_b[n - NOFF_];
            union { uint2 u; __half hx[4]; } pk;
            #pragma unroll
            for (int rr = 0; rr < 4; ++rr) {
                float v = acc[mt][nt][rr] + bia;
                if (!is_off) v = 1.f / (1.f + __expf(-v));
                pk.hx[rr] = __float2half(v);
            }
            __half* dst = is_off
                ? (off_o + ((size_t)(b * NOFF_ + n) * H_ + h) * W_ + wloc)
                : (msk_o + ((size_t)(b * NMSK_ + (n - NOFF_)) * H_ + h) * W_ + wloc);
            *(uint2*)dst = pk.u;
        }
    }
}

// ---------------- kernel 2: bilinear sample + modulated einsum (2-way split) ----
__global__ __launch_bounds__(256) void apply_partial(
    const float* __restrict__ nbr, const __half* __restrict__ off_o,
    const __half* __restrict__ msk_o, const float* __restrict__ wT,
    float* __restrict__ out)
{
    const int tid = threadIdx.x;
    // XCD swizzle over the 512 row-blocks (512 % 8 == 0, bijective)
    const int bx = blockIdx.x;
    const int bh = (bx & 7) * 64 + (bx >> 3);
    const int b = bh >> 8;
    const int h = bh & 255;
    const int w = tid;
    const int g0 = blockIdx.y * 4;

    float4 acc[16];
    #pragma unroll
    for (int j = 0; j < 16; ++j) acc[j] = make_float4(0.f, 0.f, 0.f, 0.f);

    const int pix = h * W_ + w;

    for (int gi = 0; gi < 4; ++gi) {
        const int g = g0 + gi;
        const float*  nbg  = nbr   + ((size_t)b * C_ + g * CG_) * HW_;
        const __half* offp = off_o + ((size_t)(b * NOFF_ + g * 18)) * HW_ + pix;
        const __half* mskp = msk_o + ((size_t)(b * NMSK_ + g * 9)) * HW_ + pix;
        const float*  wg   = wT + (size_t)g * (CG_ * KK_ * 64);

        float dyv[9], dxv[9], mmv[9];
        #pragma unroll
        for (int k = 0; k < 9; ++k) {
            dyv[k] = __half2float(offp[(size_t)(2*k)     * HW_]);
            dxv[k] = __half2float(offp[(size_t)(2*k + 1) * HW_]);
            mmv[k] = __half2float(mskp[(size_t)k * HW_]);
        }

        #pragma unroll 1
        for (int k = 0; k < 9; ++k) {
            float ys = (float)(h - 1 + k / 3) + dyv[k];
            float xs = (float)(w - 1 + k % 3) + dxv[k];
            float mm = mmv[k];
            float y0f = floorf(ys), x0f = floorf(xs);
            float wy = ys - y0f, wx = xs - x0f;
            int y0 = (int)y0f, x0 = (int)x0f;
            int y1 = y0 + 1, x1 = x0 + 1;
            int yc0 = min(max(y0, 0), H_-1), yc1 = min(max(y1, 0), H_-1);
            float wy0v = (1.f - wy) * (((unsigned)y0 < H_) ? mm : 0.f);
            float wy1v = wy * (((unsigned)y1 < H_) ? mm : 0.f);
            int xb = min(max(x0, 0), W_-2);
            float wx0v = (((unsigned)x0 < W_) ? (1.f - wx) : 0.f);
            float wx1v = (((unsigned)x1 < W_) ? wx : 0.f);
            float sx0 = (x0 == xb) ? wx0v : ((x1 == xb) ? wx1v : 0.f);
            float sx1 = (x1 == xb + 1) ? wx1v : ((x0 == xb + 1) ? wx0v : 0.f);
            int o0 = yc0 * W_ + xb, o1 = yc1 * W_ + xb;
            #pragma unroll
            for (int c = 0; c < CG_; ++c) {
                const float* pch = nbg + (size_t)c * HW_;
                float2 r0 = *(const float2*)(pch + o0);
                float2 r1 = *(const float2*)(pch + o1);
                float v = wy0v * (sx0 * r0.x + sx1 * r0.y)
                        + wy1v * (sx0 * r1.x + sx1 * r1.y);
                const float* wp = wg + (c * 9 + k) * 64;   // wave-uniform -> s_load
                #pragma unroll
                for (int j = 0; j < 16; ++j) {
                    float4 wv = *(const float4*)(wp + 4*j);
                    acc[j].x += v * wv.x;
                    acc[j].y += v * wv.y;
                    acc[j].z += v * wv.z;
                    acc[j].w += v * wv.w;
                }
            }
        }
    }

    float* op = out + (size_t)b * C_ * HW_ + pix;
    #pragma unroll
    for (int j = 0; j < 16; ++j) {
        atomicAdd(op + (size_t)(4*j+0)*HW_, acc[j].x);
        atomicAdd(op + (size_t)(4*j+1)*HW_, acc[j].y);
        atomicAdd(op + (size_t)(4*j+2)*HW_, acc[j].z);
        atomicAdd(op + (size_t)(4*j+3)*HW_, acc[j].w);
    }
}

extern "C" void kernel_launch(void* const* d_in, const int* in_sizes, int n_in,
                              void* d_out, int out_size, void* d_ws, size_t ws_size,
                              hipStream_t stream) {
    const float* ref    = (const float*)d_in[0];
    const float* nbr    = (const float*)d_in[1];
    const float* off_w  = (const float*)d_in[2];
    const float* off_b  = (const float*)d_in[3];
    const float* msk_w  = (const float*)d_in[4];
    const float* msk_b  = (const float*)d_in[5];
    const float* weight = (const float*)d_in[6];
    const float* bias   = (const float*)d_in[7];
    float* out = (float*)d_out;

    // ws carve: wT fp32 | off f16 | msk f16 | Bw2 bf16 | xp chunk-planar bf16
    const size_t sz_wT  = (size_t)64 * 576 * 4;              // 147456
    const size_t sz_off = (size_t)B_ * NOFF_ * HW_ * 2;      // 37748736
    const size_t sz_msk = (size_t)B_ * NMSK_ * HW_ * 2;      // 18874368
    const size_t sz_Bw  = (size_t)36 * 256 * 32 * 2;         // 589824

    char* ws = (char*)d_ws;
    float*  wT    = (float*)ws;
    __half* off_o = (__half*)(ws + sz_wT);
    __half* msk_o = (__half*)(ws + sz_wT + sz_off);
    short*  Bw    = (short*)(ws + sz_wT + sz_off + sz_msk);
    short*  xp    = (short*)(ws + sz_wT + sz_off + sz_msk + sz_Bw);

    wtrans_kernel<<<144, 256, 0, stream>>>(weight, wT);
    wtrans2_kernel<<<1152, 256, 0, stream>>>(off_w, msk_w, Bw);
    pack_xp2<<<dim3(B_ * XPH_, 4), 256, 0, stream>>>(ref, nbr, xp);
    init_out<<<8192, 256, 0, stream>>>(bias, out);
    conv_mfma<<<1024, 256, 0, stream>>>(xp, Bw, off_b, msk_b, off_o, msk_o);
    apply_partial<<<dim3(512, 2), 256, 0, stream>>>(nbr, off_o, msk_o, wT, out);
}

// Round 3
// 375.040 us; speedup vs baseline: 1.4699x; 1.0658x over previous
//
#include <hip/hip_runtime.h>
#include <hip/hip_fp16.h>
#include <cstdint>
#include <cstddef>

#define B_ 2
#define C_ 64
#define H_ 256
#define W_ 256
#define HW_ (H_*W_)
#define DG_ 8
#define CG_ 8
#define KK_ 9
#define NOFF_ 144
#define NMSK_ 72
#define NTOT_ 216
#define KRED_ 1152   // 128 * 9
#define XPH_ 258     // padded spatial dim (H+2)

typedef __bf16 bf16x8 __attribute__((ext_vector_type(8)));
typedef _Float16 half8 __attribute__((ext_vector_type(8)));
typedef short  short8 __attribute__((ext_vector_type(8)));
typedef float  f32x4  __attribute__((ext_vector_type(4)));

__device__ __forceinline__ short f2bf(float f) {
    union { float f; uint32_t u; } a; a.f = f;
    uint32_t u = a.u;
    uint32_t r = (u + 0x7fffu + ((u >> 16) & 1u)) >> 16;
    return (short)r;
}

// async global->LDS, 16B per lane: dest = wave-uniform base + lane*16
typedef __attribute__((address_space(1))) const unsigned int g_u32;
typedef __attribute__((address_space(3))) unsigned int l_u32;
__device__ __forceinline__ void gl_lds16(const void* g, void* l) {
    __builtin_amdgcn_global_load_lds((g_u32*)g, (l_u32*)l, 16, 0, 0);
}

// ------ kernel 0b: conv weights -> bf16, step-major, slot-swizzled, 256 rows ----
// Bw[s][n][slot][8ch], s = c4*9 + tap; stored slot = q ^ ((n>>1)&3)
__global__ void wtrans2_kernel(const float* __restrict__ off_w,
                               const float* __restrict__ msk_w,
                               short* __restrict__ Bw) {
    int idx = blockIdx.x * 256 + threadIdx.x;   // 36*256*32 = 294912
    int s    = idx >> 13;          // 8192 shorts per step
    int rem  = idx & 8191;
    int n    = rem >> 5;
    int slot = (rem >> 3) & 3;
    int j    = rem & 7;
    int q    = slot ^ ((n >> 1) & 3);
    int c4   = s / 9;
    int tap  = s - c4 * 9;
    int ch   = c4 * 32 + q * 8 + j;
    float v = 0.f;
    if (n < NOFF_)      v = off_w[(size_t)n * KRED_ + ch * 9 + tap];
    else if (n < NTOT_) v = msk_w[(size_t)(n - NOFF_) * KRED_ + ch * 9 + tap];
    Bw[idx] = f2bf(v);
}

// ------ kernel 0f: apply weights -> f16 chunk-major [18][64][slot4][8] ---------
// kc chunk: k = kc>>1, g = (kc&1)*4 + q, c = j; stored slot = q ^ ((n>>1)&3)
__global__ void wtrans3_kernel(const float* __restrict__ weight,
                               short* __restrict__ Bw3) {
    int idx = blockIdx.x * 256 + threadIdx.x;   // 18*2048 = 36864
    int kc   = idx >> 11;
    int rem  = idx & 2047;
    int n    = rem >> 5;
    int slot = (rem >> 3) & 3;
    int j    = rem & 7;
    int q    = slot ^ ((n >> 1) & 3);
    int k    = kc >> 1;
    int g    = ((kc & 1) << 2) + q;
    int ci   = g * 8 + j;
    union { _Float16 h; short s; } cv;
    cv.h = (_Float16)weight[((size_t)n * 64 + ci) * 9 + k];
    Bw3[idx] = cv.s;
}

// ------- kernel 0e: pack concat(ref,nbr) -> chunk-planar padded bf16 ------------
// xp[b][c4][yi 258][xi 258][slot 4][8ch]; stored slot = q ^ ((xi>>1)&3); zero pad
__global__ void pack_xp2(const float* __restrict__ ref,
                         const float* __restrict__ nbr,
                         short* __restrict__ xp) {
    const int by = blockIdx.x;          // b*258 + yi
    const int b  = by / XPH_;
    const int yi = by - b * XPH_;
    const int c4 = blockIdx.y;
    const int yg = yi - 1;
    const float* base = (c4 < 2 ? ref : nbr) + ((size_t)b * 64 + (c4 & 1) * 32) * HW_;
    short* rowbase = xp + (((size_t)(b * 4 + c4) * XPH_ + yi) * XPH_) * 32;
    for (int xi = threadIdx.x; xi < XPH_; xi += 256) {
        const int xg = xi - 1;
        const bool valid = ((unsigned)yg < H_) && ((unsigned)xg < W_);
        short* dst = rowbase + (size_t)xi * 32;
        const int sig = (xi >> 1) & 3;
        #pragma unroll
        for (int q = 0; q < 4; ++q) {
            short8 o;
            if (valid) {
                const float* p = base + (size_t)(q * 8) * HW_ + (size_t)yg * W_ + xg;
                #pragma unroll
                for (int j = 0; j < 8; ++j) o[j] = f2bf(p[(size_t)j * HW_]);
            } else {
                #pragma unroll
                for (int j = 0; j < 8; ++j) o[j] = 0;
            }
            *reinterpret_cast<short8*>(dst + ((q ^ sig) * 8)) = o;
        }
    }
}

// ---------------- kernel 1: offset/mask conv — 2-phase double-buffered ----------
__global__ __launch_bounds__(256, 2) void conv_mfma(
    const short* __restrict__ xp, const short* __restrict__ Bw,
    const float* __restrict__ off_b, const float* __restrict__ msk_b,
    __half* __restrict__ off_o, __half* __restrict__ msk_o)
{
    __shared__ __align__(16) short As[2][128 * 32];   // 8 KB each
    __shared__ __align__(16) short Bs[2][256 * 32];   // 16 KB each

    const int tid  = threadIdx.x;
    const int lane = tid & 63;
    const int wid  = tid >> 6;
    const int wm   = wid & 1;
    const int wn   = wid >> 1;
    const int col     = lane & 15;
    const int quad    = lane >> 4;
    const int rowbase = quad * 4;

    // XCD-aware bijective swizzle (1024 blocks % 8 == 0)
    const int bid = blockIdx.x;
    const int wg  = (bid & 7) * 128 + (bid >> 3);
    const int m0 = wg << 7;
    const int b  = m0 >> 16;
    const int h  = (m0 >> 8) & 255;
    const int w0 = m0 & 255;

    int bOff[8];
    #pragma unroll
    for (int nt = 0; nt < 8; ++nt) {
        int n = wn * 128 + nt * 16 + col;
        bOff[nt] = (n * 4 + (quad ^ ((n >> 1) & 3))) * 8;
    }
    int pxv[4];
    #pragma unroll
    for (int mt = 0; mt < 4; ++mt) pxv[mt] = wm * 64 + mt * 16 + col;

    f32x4 acc[4][8];
    #pragma unroll
    for (int i = 0; i < 4; ++i)
        #pragma unroll
        for (int j = 0; j < 8; ++j) acc[i][j] = f32x4{0.f, 0.f, 0.f, 0.f};

    auto stage = [&](int s, int bb) {
        const int c4s = s / 9;
        const int tp  = s - c4s * 9;
        const int dys = tp / 3;
        const int dxs = tp - dys * 3;
        const short* sA = xp + ((((size_t)(b * 4 + c4s) * XPH_ + (h + dys)) * XPH_
                                 + (w0 + dxs)) << 5);
        char* dA = (char*)&As[bb][0];
        gl_lds16(sA + (size_t)tid * 8,         dA + wid * 1024);
        gl_lds16(sA + (size_t)(256 + tid) * 8, dA + 4096 + wid * 1024);
        const short* sB = Bw + ((size_t)s << 13);
        char* dB = (char*)&Bs[bb][0];
        #pragma unroll
        for (int i = 0; i < 4; ++i)
            gl_lds16(sB + (size_t)(i * 256 + tid) * 8, dB + i * 4096 + wid * 1024);
    };

    stage(0, 0);
    __syncthreads();

    #pragma unroll 1
    for (int s = 0; s < 36; ++s) {
        const int bb = s & 1;
        if (s < 35) stage(s + 1, bb ^ 1);

        const int tp  = s - (s / 9) * 9;
        const int dxc = tp - (tp / 3) * 3;
        const short* AsC = &As[bb][0];
        const short* BsC = &Bs[bb][0];

        bf16x8 af[4], bv[8];
        #pragma unroll
        for (int mt = 0; mt < 4; ++mt) {
            const int px = pxv[mt];
            const int slot = quad ^ (((dxc + px) >> 1) & 3);
            af[mt] = *reinterpret_cast<const bf16x8*>(&AsC[(px * 4 + slot) * 8]);
        }
        #pragma unroll
        for (int nt = 0; nt < 8; ++nt)
            bv[nt] = *reinterpret_cast<const bf16x8*>(&BsC[bOff[nt]]);

        #pragma unroll
        for (int mt = 0; mt < 4; ++mt)
            #pragma unroll
            for (int nt = 0; nt < 8; ++nt)
                acc[mt][nt] = __builtin_amdgcn_mfma_f32_16x16x32_bf16(
                    af[mt], bv[nt], acc[mt][nt], 0, 0, 0);

        __syncthreads();
    }

    #pragma unroll
    for (int mt = 0; mt < 4; ++mt) {
        const int wloc = w0 + wm * 64 + mt * 16 + rowbase;
        #pragma unroll
        for (int nt = 0; nt < 8; ++nt) {
            const int n = wn * 128 + nt * 16 + col;
            if (n >= NTOT_) continue;
            const bool is_off = (n < NOFF_);
            const float bia = is_off ? off_b[n] : msk_b[n - NOFF_];
            union { uint2 u; __half hx[4]; } pk;
            #pragma unroll
            for (int rr = 0; rr < 4; ++rr) {
                float v = acc[mt][nt][rr] + bia;
                if (!is_off) v = 1.f / (1.f + __expf(-v));
                pk.hx[rr] = __float2half(v);
            }
            __half* dst = is_off
                ? (off_o + ((size_t)(b * NOFF_ + n) * H_ + h) * W_ + wloc)
                : (msk_o + ((size_t)(b * NMSK_ + (n - NOFF_)) * H_ + h) * W_ + wloc);
            *(uint2*)dst = pk.u;
        }
    }
}

// ------- kernel 2: bilinear sample + modulated einsum via f16 MFMA --------------
// block = 128 px (one h-row segment) x all 64 outputs, K=576 in 18 chunks of 32.
// chunk kc: k = kc>>1, groups (kc&1)*4 .. +3. No atomics: full K per block.
__global__ __launch_bounds__(512, 2) void apply_mfma(
    const float* __restrict__ nbr, const __half* __restrict__ off_o,
    const __half* __restrict__ msk_o, const short* __restrict__ Bw3,
    const float* __restrict__ bias, float* __restrict__ out)
{
    __shared__ __align__(16) short As[2][128 * 32];   // 8 KB each
    __shared__ __align__(16) short Bs[2][64 * 32];    // 4 KB each

    const int tid  = threadIdx.x;
    const int lane = tid & 63;
    const int wid  = tid >> 6;          // 0..7
    const int col  = lane & 15;
    const int quad = lane >> 4;
    const int wm   = wid & 1;           // px half (64)
    const int wn   = wid >> 1;          // out quarter (16)

    const int bid = blockIdx.x;
    const int wg  = (bid & 7) * 128 + (bid >> 3);   // XCD swizzle, 1024 % 8 == 0
    const int m0  = wg << 7;
    const int b   = m0 >> 16;
    const int h   = (m0 >> 8) & 255;
    const int w0  = m0 & 255;

    const int p     = tid & 127;        // pixel within tile
    const int q     = tid >> 7;         // 0..3: group-slot within chunk
    const int w     = w0 + p;
    const int pix   = h * W_ + w;
    const int slotW = q ^ ((p >> 1) & 3);

    auto stageA = [&](int kc, int bb) {
        const int k  = kc >> 1;
        const int gs = (kc & 1) << 2;
        const int g  = gs + q;
        const int ky = k / 3;
        const int kx = k - ky * 3;
        float dyv = __half2float(off_o[((size_t)(b * NOFF_ + g * 18 + 2 * k)) * HW_ + pix]);
        float dxv = __half2float(off_o[((size_t)(b * NOFF_ + g * 18 + 2 * k + 1)) * HW_ + pix]);
        float mm  = __half2float(msk_o[((size_t)(b * NMSK_ + g * 9 + k)) * HW_ + pix]);
        float ys = (float)(h - 1 + ky) + dyv;
        float xs = (float)(w - 1 + kx) + dxv;
        float y0f = floorf(ys), x0f = floorf(xs);
        float wy = ys - y0f, wx = xs - x0f;
        int y0 = (int)y0f, x0 = (int)x0f;
        int y1 = y0 + 1, x1 = x0 + 1;
        int yc0 = min(max(y0, 0), H_-1), yc1 = min(max(y1, 0), H_-1);
        float wy0v = (1.f - wy) * (((unsigned)y0 < H_) ? mm : 0.f);
        float wy1v = wy * (((unsigned)y1 < H_) ? mm : 0.f);
        int xb = min(max(x0, 0), W_-2);
        float wx0v = (((unsigned)x0 < W_) ? (1.f - wx) : 0.f);
        float wx1v = (((unsigned)x1 < W_) ? wx : 0.f);
        float sx0 = (x0 == xb) ? wx0v : ((x1 == xb) ? wx1v : 0.f);
        float sx1 = (x1 == xb + 1) ? wx1v : ((x0 == xb + 1) ? wx0v : 0.f);
        int o0 = yc0 * W_ + xb, o1 = yc1 * W_ + xb;
        const float* nbg = nbr + ((size_t)b * C_ + g * CG_) * HW_;
        union { half8 h8; short8 s8; } u;
        #pragma unroll
        for (int c = 0; c < CG_; ++c) {
            const float* pch = nbg + (size_t)c * HW_;
            float2 r0 = *(const float2*)(pch + o0);
            float2 r1 = *(const float2*)(pch + o1);
            float v = wy0v * (sx0 * r0.x + sx1 * r0.y)
                    + wy1v * (sx0 * r1.x + sx1 * r1.y);
            u.h8[c] = (_Float16)v;
        }
        *reinterpret_cast<short8*>(&As[bb][(p * 4 + slotW) * 8]) = u.s8;
    };
    auto stageB = [&](int kc, int bb) {
        if (wid < 4)
            gl_lds16(Bw3 + ((size_t)kc << 11) + tid * 8,
                     (char*)&Bs[bb][0] + wid * 1024);
    };

    f32x4 acc[4];
    #pragma unroll
    for (int mt = 0; mt < 4; ++mt) acc[mt] = f32x4{0.f, 0.f, 0.f, 0.f};

    stageB(0, 0);
    stageA(0, 0);
    __syncthreads();

    #pragma unroll 1
    for (int kc = 0; kc < 18; ++kc) {
        const int bb = kc & 1;
        const short* AsC = &As[bb][0];
        const short* BsC = &Bs[bb][0];

        // frag ds_reads first (so MFMA's lgkmcnt wait excludes the stage writes)
        half8 af[4], bv;
        {
            const int n = wn * 16 + col;
            bv = *reinterpret_cast<const half8*>(
                &BsC[(n * 4 + (quad ^ ((n >> 1) & 3))) * 8]);
        }
        #pragma unroll
        for (int mt = 0; mt < 4; ++mt) {
            const int px = wm * 64 + mt * 16 + col;
            af[mt] = *reinterpret_cast<const half8*>(
                &AsC[(px * 4 + (quad ^ ((px >> 1) & 3))) * 8]);
        }

        if (kc < 17) { stageB(kc + 1, bb ^ 1); stageA(kc + 1, bb ^ 1); }

        #pragma unroll
        for (int mt = 0; mt < 4; ++mt)
            acc[mt] = __builtin_amdgcn_mfma_f32_16x16x32_f16(af[mt], bv, acc[mt], 0, 0, 0);

        __syncthreads();
    }

    const int o = wn * 16 + col;
    const float bo = bias[o];
    float* op = out + ((size_t)b * C_ + o) * HW_ + (size_t)h * W_ + w0;
    #pragma unroll
    for (int mt = 0; mt < 4; ++mt) {
        const int px = wm * 64 + mt * 16 + quad * 4;
        float4 st = make_float4(acc[mt][0] + bo, acc[mt][1] + bo,
                                acc[mt][2] + bo, acc[mt][3] + bo);
        *(float4*)(op + px) = st;
    }
}

extern "C" void kernel_launch(void* const* d_in, const int* in_sizes, int n_in,
                              void* d_out, int out_size, void* d_ws, size_t ws_size,
                              hipStream_t stream) {
    const float* ref    = (const float*)d_in[0];
    const float* nbr    = (const float*)d_in[1];
    const float* off_w  = (const float*)d_in[2];
    const float* off_b  = (const float*)d_in[3];
    const float* msk_w  = (const float*)d_in[4];
    const float* msk_b  = (const float*)d_in[5];
    const float* weight = (const float*)d_in[6];
    const float* bias   = (const float*)d_in[7];
    float* out = (float*)d_out;

    // ws carve: off f16 | msk f16 | Bw bf16 | xp chunk-planar bf16 | Bw3 f16
    const size_t sz_off = (size_t)B_ * NOFF_ * HW_ * 2;      // 37748736
    const size_t sz_msk = (size_t)B_ * NMSK_ * HW_ * 2;      // 18874368
    const size_t sz_Bw  = (size_t)36 * 256 * 32 * 2;         // 589824
    const size_t sz_xp  = (size_t)B_ * 4 * XPH_ * XPH_ * 32 * 2; // 34080768

    char* ws = (char*)d_ws;
    __half* off_o = (__half*)ws;
    __half* msk_o = (__half*)(ws + sz_off);
    short*  Bw    = (short*)(ws + sz_off + sz_msk);
    short*  xp    = (short*)(ws + sz_off + sz_msk + sz_Bw);
    short*  Bw3   = (short*)(ws + sz_off + sz_msk + sz_Bw + sz_xp);

    wtrans2_kernel<<<1152, 256, 0, stream>>>(off_w, msk_w, Bw);
    wtrans3_kernel<<<144, 256, 0, stream>>>(weight, Bw3);
    pack_xp2<<<dim3(B_ * XPH_, 4), 256, 0, stream>>>(ref, nbr, xp);
    conv_mfma<<<1024, 256, 0, stream>>>(xp, Bw, off_b, msk_b, off_o, msk_o);
    apply_mfma<<<1024, 512, 0, stream>>>(nbr, off_o, msk_o, Bw3, bias, out);
}

// Round 4
// 353.716 us; speedup vs baseline: 1.5585x; 1.0603x over previous
//
#include <hip/hip_runtime.h>
#include <hip/hip_fp16.h>
#include <cstdint>
#include <cstddef>

#define B_ 2
#define C_ 64
#define H_ 256
#define W_ 256
#define HW_ (H_*W_)
#define DG_ 8
#define CG_ 8
#define KK_ 9
#define NOFF_ 144
#define NMSK_ 72
#define NTOT_ 216
#define KRED_ 1152   // 128 * 9
#define XPH_ 258     // padded spatial dim (H+2)

typedef __bf16 bf16x8 __attribute__((ext_vector_type(8)));
typedef _Float16 half8 __attribute__((ext_vector_type(8)));
typedef short  short8 __attribute__((ext_vector_type(8)));
typedef float  f32x4  __attribute__((ext_vector_type(4)));

__device__ __forceinline__ short f2bf(float f) {
    union { float f; uint32_t u; } a; a.f = f;
    uint32_t u = a.u;
    uint32_t r = (u + 0x7fffu + ((u >> 16) & 1u)) >> 16;
    return (short)r;
}

// async global->LDS, 16B per lane: dest = wave-uniform base + lane*16
typedef __attribute__((address_space(1))) const unsigned int g_u32;
typedef __attribute__((address_space(3))) unsigned int l_u32;
__device__ __forceinline__ void gl_lds16(const void* g, void* l) {
    __builtin_amdgcn_global_load_lds((g_u32*)g, (l_u32*)l, 16, 0, 0);
}

// ------ kernel 0b: conv weights -> bf16, step-major, slot-swizzled, 256 rows ----
// Bw[s][n][slot][8ch], s = c4*9 + tap; stored slot = q ^ ((n>>1)&3)
__global__ void wtrans2_kernel(const float* __restrict__ off_w,
                               const float* __restrict__ msk_w,
                               short* __restrict__ Bw) {
    int idx = blockIdx.x * 256 + threadIdx.x;   // 36*256*32 = 294912
    int s    = idx >> 13;          // 8192 shorts per step
    int rem  = idx & 8191;
    int n    = rem >> 5;
    int slot = (rem >> 3) & 3;
    int j    = rem & 7;
    int q    = slot ^ ((n >> 1) & 3);
    int c4   = s / 9;
    int tap  = s - c4 * 9;
    int ch   = c4 * 32 + q * 8 + j;
    float v = 0.f;
    if (n < NOFF_)      v = off_w[(size_t)n * KRED_ + ch * 9 + tap];
    else if (n < NTOT_) v = msk_w[(size_t)(n - NOFF_) * KRED_ + ch * 9 + tap];
    Bw[idx] = f2bf(v);
}

// ------ kernel 0f: apply weights -> f16 chunk-major [18][64][slot4][8] ---------
// kc chunk: k = kc>>1, g = (kc&1)*4 + q, c = j; stored slot = q ^ ((n>>1)&3)
__global__ void wtrans3_kernel(const float* __restrict__ weight,
                               short* __restrict__ Bw3) {
    int idx = blockIdx.x * 256 + threadIdx.x;   // 18*2048 = 36864
    int kc   = idx >> 11;
    int rem  = idx & 2047;
    int n    = rem >> 5;
    int slot = (rem >> 3) & 3;
    int j    = rem & 7;
    int q    = slot ^ ((n >> 1) & 3);
    int k    = kc >> 1;
    int g    = ((kc & 1) << 2) + q;
    int ci   = g * 8 + j;
    union { _Float16 h; short s; } cv;
    cv.h = (_Float16)weight[((size_t)n * 64 + ci) * 9 + k];
    Bw3[idx] = cv.s;
}

// ------- kernel 0e: pack concat(ref,nbr) -> chunk-planar padded bf16 ------------
// xp[b][c4][yi 258][xi 258][slot 4][8ch]; stored slot = q ^ ((xi>>1)&3); zero pad
// fused: for c4>=2 (nbr channels) also emit nbf[b][g][y][x][8ch] f16 (no pad)
__global__ void pack_xp2(const float* __restrict__ ref,
                         const float* __restrict__ nbr,
                         short* __restrict__ xp,
                         short* __restrict__ nbf) {
    const int by = blockIdx.x;          // b*258 + yi
    const int b  = by / XPH_;
    const int yi = by - b * XPH_;
    const int c4 = blockIdx.y;
    const int yg = yi - 1;
    const float* base = (c4 < 2 ? ref : nbr) + ((size_t)b * 64 + (c4 & 1) * 32) * HW_;
    short* rowbase = xp + (((size_t)(b * 4 + c4) * XPH_ + yi) * XPH_) * 32;
    for (int xi = threadIdx.x; xi < XPH_; xi += 256) {
        const int xg = xi - 1;
        const bool valid = ((unsigned)yg < H_) && ((unsigned)xg < W_);
        short* dst = rowbase + (size_t)xi * 32;
        const int sig = (xi >> 1) & 3;
        #pragma unroll
        for (int q = 0; q < 4; ++q) {
            float v[8];
            if (valid) {
                const float* p = base + (size_t)(q * 8) * HW_ + (size_t)yg * W_ + xg;
                #pragma unroll
                for (int j = 0; j < 8; ++j) v[j] = p[(size_t)j * HW_];
            } else {
                #pragma unroll
                for (int j = 0; j < 8; ++j) v[j] = 0.f;
            }
            short8 o;
            #pragma unroll
            for (int j = 0; j < 8; ++j) o[j] = f2bf(v[j]);
            *reinterpret_cast<short8*>(dst + ((q ^ sig) * 8)) = o;
            if (c4 >= 2 && valid) {
                const int g = (c4 - 2) * 4 + q;
                union { half8 h8; short8 s8; } u;
                #pragma unroll
                for (int j = 0; j < 8; ++j) u.h8[j] = (_Float16)v[j];
                *reinterpret_cast<short8*>(
                    nbf + ((size_t)(b * 8 + g) * HW_ + (size_t)yg * W_ + xg) * 8) = u.s8;
            }
        }
    }
}

// ---------------- kernel 1: offset/mask conv — window-staged A, register B ------
// 12 windows (c4,dy), 3 taps each; A staged once per window (136 px), B fragments
// read direct from global (L1/L2-hot 590 KB) with 2-deep register pipeline.
__global__ __launch_bounds__(256, 2) void conv_mfma(
    const short* __restrict__ xp, const short* __restrict__ Bw,
    const float* __restrict__ off_b, const float* __restrict__ msk_b,
    __half* __restrict__ off_o, __half* __restrict__ msk_o)
{
    __shared__ __align__(16) short As[2][144 * 32];   // 9 KB each (136 px used)

    const int tid  = threadIdx.x;
    const int lane = tid & 63;
    const int wid  = tid >> 6;
    const int wm   = wid & 1;
    const int wn   = wid >> 1;
    const int col     = lane & 15;
    const int quad    = lane >> 4;
    const int rowbase = quad * 4;

    // XCD-aware bijective swizzle (1024 blocks % 8 == 0)
    const int bid = blockIdx.x;
    const int wg  = (bid & 7) * 128 + (bid >> 3);
    const int m0 = wg << 7;
    const int b  = m0 >> 16;
    const int h  = (m0 >> 8) & 255;
    const int w0 = m0 & 255;

    int bOff[8];
    #pragma unroll
    for (int nt = 0; nt < 8; ++nt) {
        int n = wn * 128 + nt * 16 + col;
        bOff[nt] = (n * 4 + (quad ^ ((n >> 1) & 3))) * 8;
    }
    int pxv[4];
    #pragma unroll
    for (int mt = 0; mt < 4; ++mt) pxv[mt] = wm * 64 + mt * 16 + col;

    f32x4 acc[4][8];
    #pragma unroll
    for (int i = 0; i < 4; ++i)
        #pragma unroll
        for (int j = 0; j < 8; ++j) acc[i][j] = f32x4{0.f, 0.f, 0.f, 0.f};

    // stage one (c4,dy) A-window: 136 px starting at w0 (covers all 3 taps)
    auto stageA = [&](int win, int bb) {
        const int c4s = win / 3;
        const int dys = win - c4s * 3;
        const short* sA = xp + (((size_t)(b * 4 + c4s) * XPH_ + (h + dys)) * XPH_
                                + w0) * 32;
        char* dA = (char*)&As[bb][0];
        gl_lds16(sA + (size_t)tid * 8,         dA + wid * 1024);
        gl_lds16(sA + (size_t)(256 + tid) * 8, dA + 4096 + wid * 1024);
        if (tid < 32) gl_lds16(sA + (size_t)(512 + tid) * 8, dA + 8192);
    };

    bf16x8 bvA[8], bvB[8];
    {
        const short* bp = Bw;   // s = 0
        #pragma unroll
        for (int nt = 0; nt < 8; ++nt)
            bvA[nt] = *reinterpret_cast<const bf16x8*>(bp + bOff[nt]);
    }

    stageA(0, 0);
    __syncthreads();

    const short* bwin = Bw;     // base for window's s = win*3
    #pragma unroll 1
    for (int win = 0; win < 12; ++win) {
        const int bb = win & 1;
        if (win < 11) stageA(win + 1, bb ^ 1);
        const short* AsC = &As[bb][0];

        #pragma unroll
        for (int dx = 0; dx < 3; ++dx) {
            const int s = win * 3 + dx;
            if (s < 35) {
                const short* bp = bwin + (size_t)(dx + 1) * 8192;
                #pragma unroll
                for (int nt = 0; nt < 8; ++nt)
                    bvB[nt] = *reinterpret_cast<const bf16x8*>(bp + bOff[nt]);
            }

            bf16x8 af[4];
            #pragma unroll
            for (int mt = 0; mt < 4; ++mt) {
                const int px = pxv[mt] + dx;
                af[mt] = *reinterpret_cast<const bf16x8*>(
                    &AsC[(px * 4 + (quad ^ ((px >> 1) & 3))) * 8]);
            }

            #pragma unroll
            for (int mt = 0; mt < 4; ++mt)
                #pragma unroll
                for (int nt = 0; nt < 8; ++nt)
                    acc[mt][nt] = __builtin_amdgcn_mfma_f32_16x16x32_bf16(
                        af[mt], bvA[nt], acc[mt][nt], 0, 0, 0);

            #pragma unroll
            for (int nt = 0; nt < 8; ++nt) bvA[nt] = bvB[nt];
        }
        bwin += 3 * 8192;
        __syncthreads();
    }

    #pragma unroll
    for (int mt = 0; mt < 4; ++mt) {
        const int wloc = w0 + wm * 64 + mt * 16 + rowbase;
        #pragma unroll
        for (int nt = 0; nt < 8; ++nt) {
            const int n = wn * 128 + nt * 16 + col;
            if (n >= NTOT_) continue;
            const bool is_off = (n < NOFF_);
            const float bia = is_off ? off_b[n] : msk_b[n - NOFF_];
            union { uint2 u; __half hx[4]; } pk;
            #pragma unroll
            for (int rr = 0; rr < 4; ++rr) {
                float v = acc[mt][nt][rr] + bia;
                if (!is_off) v = 1.f / (1.f + __expf(-v));
                pk.hx[rr] = __float2half(v);
            }
            __half* dst = is_off
                ? (off_o + ((size_t)(b * NOFF_ + n) * H_ + h) * W_ + wloc)
                : (msk_o + ((size_t)(b * NMSK_ + (n - NOFF_)) * H_ + h) * W_ + wloc);
            *(uint2*)dst = pk.u;
        }
    }
}

// ------- kernel 2: bilinear sample + modulated einsum via f16 MFMA --------------
// samples from group-packed f16 nbf: one 16B load per corner (8 ch at once).
// B fragments read direct from global (72 KB table). No atomics.
__global__ __launch_bounds__(512, 2) void apply_mfma(
    const short* __restrict__ nbf, const __half* __restrict__ off_o,
    const __half* __restrict__ msk_o, const short* __restrict__ Bw3,
    const float* __restrict__ bias, float* __restrict__ out)
{
    __shared__ __align__(16) short As[2][128 * 32];   // 8 KB each

    const int tid  = threadIdx.x;
    const int lane = tid & 63;
    const int wid  = tid >> 6;          // 0..7
    const int col  = lane & 15;
    const int quad = lane >> 4;
    const int wm   = wid & 1;           // px half (64)
    const int wn   = wid >> 1;          // out quarter (16)

    const int bid = blockIdx.x;
    const int wg  = (bid & 7) * 128 + (bid >> 3);   // XCD swizzle, 1024 % 8 == 0
    const int m0  = wg << 7;
    const int b   = m0 >> 16;
    const int h   = (m0 >> 8) & 255;
    const int w0  = m0 & 255;

    const int p     = tid & 127;        // pixel within tile
    const int q     = tid >> 7;         // 0..3: group-slot within chunk
    const int w     = w0 + p;
    const int pix   = h * W_ + w;
    const int slotW = q ^ ((p >> 1) & 3);

    auto stageA = [&](int kc, int bb) {
        const int k  = kc >> 1;
        const int g  = ((kc & 1) << 2) + q;
        const int ky = k / 3;
        const int kx = k - ky * 3;
        float dyv = __half2float(off_o[((size_t)(b * NOFF_ + g * 18 + 2 * k)) * HW_ + pix]);
        float dxv = __half2float(off_o[((size_t)(b * NOFF_ + g * 18 + 2 * k + 1)) * HW_ + pix]);
        float mm  = __half2float(msk_o[((size_t)(b * NMSK_ + g * 9 + k)) * HW_ + pix]);
        float ys = (float)(h - 1 + ky) + dyv;
        float xs = (float)(w - 1 + kx) + dxv;
        float y0f = floorf(ys), x0f = floorf(xs);
        float wy = ys - y0f, wx = xs - x0f;
        int y0 = (int)y0f, x0 = (int)x0f;
        int y1 = y0 + 1, x1 = x0 + 1;
        int yc0 = min(max(y0, 0), H_-1), yc1 = min(max(y1, 0), H_-1);
        float wy0v = (1.f - wy) * (((unsigned)y0 < H_) ? mm : 0.f);
        float wy1v = wy * (((unsigned)y1 < H_) ? mm : 0.f);
        int xb = min(max(x0, 0), W_-2);
        float wx0v = (((unsigned)x0 < W_) ? (1.f - wx) : 0.f);
        float wx1v = (((unsigned)x1 < W_) ? wx : 0.f);
        float sx0 = (x0 == xb) ? wx0v : ((x1 == xb) ? wx1v : 0.f);
        float sx1 = (x1 == xb + 1) ? wx1v : ((x0 == xb + 1) ? wx0v : 0.f);
        float a00 = wy0v * sx0, a01 = wy0v * sx1;
        float a10 = wy1v * sx0, a11 = wy1v * sx1;
        const short* nb = nbf + (size_t)(b * 8 + g) * HW_ * 8;
        const short* r0 = nb + ((size_t)yc0 * W_ + xb) * 8;
        const short* r1 = nb + ((size_t)yc1 * W_ + xb) * 8;
        half8 c00 = *reinterpret_cast<const half8*>(r0);
        half8 c01 = *reinterpret_cast<const half8*>(r0 + 8);
        half8 c10 = *reinterpret_cast<const half8*>(r1);
        half8 c11 = *reinterpret_cast<const half8*>(r1 + 8);
        union { half8 h8; short8 s8; } u;
        #pragma unroll
        for (int c = 0; c < CG_; ++c) {
            float v = a00 * (float)c00[c] + a01 * (float)c01[c]
                    + a10 * (float)c10[c] + a11 * (float)c11[c];
            u.h8[c] = (_Float16)v;
        }
        *reinterpret_cast<short8*>(&As[bb][(p * 4 + slotW) * 8]) = u.s8;
    };

    // per-thread B fragment address (contiguous 1 KB per wave, L1/L2-hot)
    const int nB = wn * 16 + col;
    const short* bPtr = Bw3 + ((nB * 4 + (quad ^ ((nB >> 1) & 3))) << 3);

    f32x4 acc[4];
    #pragma unroll
    for (int mt = 0; mt < 4; ++mt) acc[mt] = f32x4{0.f, 0.f, 0.f, 0.f};

    stageA(0, 0);
    __syncthreads();

    #pragma unroll 1
    for (int kc = 0; kc < 18; ++kc) {
        const int bb = kc & 1;
        const short* AsC = &As[bb][0];

        half8 bv = *reinterpret_cast<const half8*>(bPtr + ((size_t)kc << 11));
        half8 af[4];
        #pragma unroll
        for (int mt = 0; mt < 4; ++mt) {
            const int px = wm * 64 + mt * 16 + col;
            af[mt] = *reinterpret_cast<const half8*>(
                &AsC[(px * 4 + (quad ^ ((px >> 1) & 3))) * 8]);
        }

        if (kc < 17) stageA(kc + 1, bb ^ 1);

        #pragma unroll
        for (int mt = 0; mt < 4; ++mt)
            acc[mt] = __builtin_amdgcn_mfma_f32_16x16x32_f16(af[mt], bv, acc[mt], 0, 0, 0);

        __syncthreads();
    }

    const int o = wn * 16 + col;
    const float bo = bias[o];
    float* op = out + ((size_t)b * C_ + o) * HW_ + (size_t)h * W_ + w0;
    #pragma unroll
    for (int mt = 0; mt < 4; ++mt) {
        const int px = wm * 64 + mt * 16 + quad * 4;
        float4 st = make_float4(acc[mt][0] + bo, acc[mt][1] + bo,
                                acc[mt][2] + bo, acc[mt][3] + bo);
        *(float4*)(op + px) = st;
    }
}

extern "C" void kernel_launch(void* const* d_in, const int* in_sizes, int n_in,
                              void* d_out, int out_size, void* d_ws, size_t ws_size,
                              hipStream_t stream) {
    const float* ref    = (const float*)d_in[0];
    const float* nbr    = (const float*)d_in[1];
    const float* off_w  = (const float*)d_in[2];
    const float* off_b  = (const float*)d_in[3];
    const float* msk_w  = (const float*)d_in[4];
    const float* msk_b  = (const float*)d_in[5];
    const float* weight = (const float*)d_in[6];
    const float* bias   = (const float*)d_in[7];
    float* out = (float*)d_out;

    // ws carve: off f16 | msk f16 | Bw bf16 | xp (+16KB pad) | Bw3 f16 | nbf f16
    const size_t sz_off = (size_t)B_ * NOFF_ * HW_ * 2;          // 37748736
    const size_t sz_msk = (size_t)B_ * NMSK_ * HW_ * 2;          // 18874368
    const size_t sz_Bw  = (size_t)36 * 256 * 32 * 2;             // 589824
    const size_t sz_xp  = (size_t)B_ * 4 * XPH_ * XPH_ * 32 * 2
                          + 16384;                               // 34097152
    const size_t sz_Bw3 = (size_t)18 * 64 * 32 * 2;              // 73728

    char* ws = (char*)d_ws;
    __half* off_o = (__half*)ws;
    __half* msk_o = (__half*)(ws + sz_off);
    short*  Bw    = (short*)(ws + sz_off + sz_msk);
    short*  xp    = (short*)(ws + sz_off + sz_msk + sz_Bw);
    short*  Bw3   = (short*)(ws + sz_off + sz_msk + sz_Bw + sz_xp);
    short*  nbf   = (short*)(ws + sz_off + sz_msk + sz_Bw + sz_xp + sz_Bw3);

    wtrans2_kernel<<<1152, 256, 0, stream>>>(off_w, msk_w, Bw);
    wtrans3_kernel<<<144, 256, 0, stream>>>(weight, Bw3);
    pack_xp2<<<dim3(B_ * XPH_, 4), 256, 0, stream>>>(ref, nbr, xp, nbf);
    conv_mfma<<<1024, 256, 0, stream>>>(xp, Bw, off_b, msk_b, off_o, msk_o);
    apply_mfma<<<1024, 512, 0, stream>>>(nbf, off_o, msk_o, Bw3, bias, out);
}

// Round 5
// 265.767 us; speedup vs baseline: 2.0743x; 1.3309x over previous
//
#include <hip/hip_runtime.h>
#include <hip/hip_fp16.h>
#include <cstdint>
#include <cstddef>

#define B_ 2
#define C_ 64
#define H_ 256
#define W_ 256
#define HW_ (H_*W_)
#define DG_ 8
#define CG_ 8
#define KK_ 9
#define NOFF_ 144
#define NMSK_ 72
#define NTOT_ 216
#define KRED_ 1152   // 128 * 9
#define XPH_ 258     // padded spatial dim (H+2)

typedef __bf16 bf16x8 __attribute__((ext_vector_type(8)));
typedef _Float16 half8 __attribute__((ext_vector_type(8)));
typedef short  short8 __attribute__((ext_vector_type(8)));
typedef float  f32x4  __attribute__((ext_vector_type(4)));

__device__ __forceinline__ short f2bf(float f) {
    union { float f; uint32_t u; } a; a.f = f;
    uint32_t u = a.u;
    uint32_t r = (u + 0x7fffu + ((u >> 16) & 1u)) >> 16;
    return (short)r;
}

// async global->LDS, 16B per lane: dest = wave-uniform base + lane*16
typedef __attribute__((address_space(1))) const unsigned int g_u32;
typedef __attribute__((address_space(3))) unsigned int l_u32;
__device__ __forceinline__ void gl_lds16(const void* g, void* l) {
    __builtin_amdgcn_global_load_lds((g_u32*)g, (l_u32*)l, 16, 0, 0);
}

// ------ kernel 0b: conv weights -> bf16, step-major, slot-swizzled, 256 rows ----
// Bw[s][n][slot][8ch], s = c4*9 + tap; stored slot = q ^ ((n>>1)&3)
__global__ void wtrans2_kernel(const float* __restrict__ off_w,
                               const float* __restrict__ msk_w,
                               short* __restrict__ Bw) {
    int idx = blockIdx.x * 256 + threadIdx.x;   // 36*256*32 = 294912
    int s    = idx >> 13;          // 8192 shorts per step
    int rem  = idx & 8191;
    int n    = rem >> 5;
    int slot = (rem >> 3) & 3;
    int j    = rem & 7;
    int q    = slot ^ ((n >> 1) & 3);
    int c4   = s / 9;
    int tap  = s - c4 * 9;
    int ch   = c4 * 32 + q * 8 + j;
    float v = 0.f;
    if (n < NOFF_)      v = off_w[(size_t)n * KRED_ + ch * 9 + tap];
    else if (n < NTOT_) v = msk_w[(size_t)(n - NOFF_) * KRED_ + ch * 9 + tap];
    Bw[idx] = f2bf(v);
}

// ------ kernel 0f: apply weights -> f16 chunk-major [18][64][slot4][8] ---------
// kc chunk: k = kc>>1, g = (kc&1)*4 + q, c = j; stored slot = q ^ ((n>>1)&3)
__global__ void wtrans3_kernel(const float* __restrict__ weight,
                               short* __restrict__ Bw3) {
    int idx = blockIdx.x * 256 + threadIdx.x;   // 18*2048 = 36864
    int kc   = idx >> 11;
    int rem  = idx & 2047;
    int n    = rem >> 5;
    int slot = (rem >> 3) & 3;
    int j    = rem & 7;
    int q    = slot ^ ((n >> 1) & 3);
    int k    = kc >> 1;
    int g    = ((kc & 1) << 2) + q;
    int ci   = g * 8 + j;
    union { _Float16 h; short s; } cv;
    cv.h = (_Float16)weight[((size_t)n * 64 + ci) * 9 + k];
    Bw3[idx] = cv.s;
}

// ------- kernel 0e: pack concat(ref,nbr) -> chunk-planar padded bf16 ------------
// xp[b][c4][yi 258][xi 258][slot 4][8ch]; stored slot = q ^ ((xi>>1)&3); zero pad
// fused: for c4>=2 (nbr channels) also emit nbf[b][g][y][x][8ch] f16 (no pad)
__global__ void pack_xp2(const float* __restrict__ ref,
                         const float* __restrict__ nbr,
                         short* __restrict__ xp,
                         short* __restrict__ nbf) {
    const int by = blockIdx.x;          // b*258 + yi
    const int b  = by / XPH_;
    const int yi = by - b * XPH_;
    const int c4 = blockIdx.y;
    const int yg = yi - 1;
    const float* base = (c4 < 2 ? ref : nbr) + ((size_t)b * 64 + (c4 & 1) * 32) * HW_;
    short* rowbase = xp + (((size_t)(b * 4 + c4) * XPH_ + yi) * XPH_) * 32;
    for (int xi = threadIdx.x; xi < XPH_; xi += 256) {
        const int xg = xi - 1;
        const bool valid = ((unsigned)yg < H_) && ((unsigned)xg < W_);
        short* dst = rowbase + (size_t)xi * 32;
        const int sig = (xi >> 1) & 3;
        #pragma unroll
        for (int q = 0; q < 4; ++q) {
            float v[8];
            if (valid) {
                const float* p = base + (size_t)(q * 8) * HW_ + (size_t)yg * W_ + xg;
                #pragma unroll
                for (int j = 0; j < 8; ++j) v[j] = p[(size_t)j * HW_];
            } else {
                #pragma unroll
                for (int j = 0; j < 8; ++j) v[j] = 0.f;
            }
            short8 o;
            #pragma unroll
            for (int j = 0; j < 8; ++j) o[j] = f2bf(v[j]);
            *reinterpret_cast<short8*>(dst + ((q ^ sig) * 8)) = o;
            if (c4 >= 2 && valid) {
                const int g = (c4 - 2) * 4 + q;
                union { half8 h8; short8 s8; } u;
                #pragma unroll
                for (int j = 0; j < 8; ++j) u.h8[j] = (_Float16)v[j];
                *reinterpret_cast<short8*>(
                    nbf + ((size_t)(b * 8 + g) * HW_ + (size_t)yg * W_ + xg) * 8) = u.s8;
            }
        }
    }
}

// ---------------- kernel 1: offset/mask conv — 8-wave, 64x64 wave tiles ---------
// BM=128 px, BN=256; 512 threads as 2(M)x4(N) waves; acc 64 regs/wave -> 16 w/CU.
// A window (c4,dy) staged once for 3 taps; B fragments direct from L2.
__global__ __launch_bounds__(512, 4) void conv_mfma(
    const short* __restrict__ xp, const short* __restrict__ Bw,
    const float* __restrict__ off_b, const float* __restrict__ msk_b,
    __half* __restrict__ off_o, __half* __restrict__ msk_o)
{
    __shared__ __align__(16) short As[2][4608];   // 9 KB each (136 px used)

    const int tid  = threadIdx.x;
    const int lane = tid & 63;
    const int wid  = tid >> 6;          // 0..7
    const int wm   = wid & 1;           // px half (64)
    const int wn   = wid >> 1;          // n quarter (64)
    const int col     = lane & 15;
    const int quad    = lane >> 4;
    const int rowbase = quad * 4;

    // XCD-aware bijective swizzle (1024 blocks % 8 == 0)
    const int bid = blockIdx.x;
    const int wg  = (bid & 7) * 128 + (bid >> 3);
    const int m0 = wg << 7;
    const int b  = m0 >> 16;
    const int h  = (m0 >> 8) & 255;
    const int w0 = m0 & 255;

    int bOff[4];
    #pragma unroll
    for (int nt = 0; nt < 4; ++nt) {
        int n = wn * 64 + nt * 16 + col;
        bOff[nt] = (n * 4 + (quad ^ ((n >> 1) & 3))) * 8;
    }
    int pxv[4];
    #pragma unroll
    for (int mt = 0; mt < 4; ++mt) pxv[mt] = wm * 64 + mt * 16 + col;

    f32x4 acc[4][4];
    #pragma unroll
    for (int i = 0; i < 4; ++i)
        #pragma unroll
        for (int j = 0; j < 4; ++j) acc[i][j] = f32x4{0.f, 0.f, 0.f, 0.f};

    // stage one (c4,dy) A-window: 136 px starting at w0 (covers all 3 taps)
    // 544 16B-chunks: one per thread + 32 extra via exec-masked wave 0
    auto stageA = [&](int win, int bb) {
        const int c4s = win / 3;
        const int dys = win - c4s * 3;
        const short* sA = xp + (((size_t)(b * 4 + c4s) * XPH_ + (h + dys)) * XPH_
                                + w0) * 32;
        char* dA = (char*)&As[bb][0];
        gl_lds16(sA + (size_t)tid * 8, dA + wid * 1024);
        if (tid < 32) gl_lds16(sA + (size_t)(512 + tid) * 8, dA + 8192);
    };

    stageA(0, 0);
    __syncthreads();

    #pragma unroll 1
    for (int win = 0; win < 12; ++win) {
        const int bb = win & 1;
        if (win < 11) stageA(win + 1, bb ^ 1);
        const short* AsC = &As[bb][0];

        #pragma unroll
        for (int dx = 0; dx < 3; ++dx) {
            const int s = win * 3 + dx;
            const short* bp = Bw + ((size_t)s << 13);

            bf16x8 bv[4];
            #pragma unroll
            for (int nt = 0; nt < 4; ++nt)
                bv[nt] = *reinterpret_cast<const bf16x8*>(bp + bOff[nt]);

            bf16x8 af[4];
            #pragma unroll
            for (int mt = 0; mt < 4; ++mt) {
                const int px = pxv[mt] + dx;
                af[mt] = *reinterpret_cast<const bf16x8*>(
                    &AsC[(px * 4 + (quad ^ ((px >> 1) & 3))) * 8]);
            }

            #pragma unroll
            for (int mt = 0; mt < 4; ++mt)
                #pragma unroll
                for (int nt = 0; nt < 4; ++nt)
                    acc[mt][nt] = __builtin_amdgcn_mfma_f32_16x16x32_bf16(
                        af[mt], bv[nt], acc[mt][nt], 0, 0, 0);
        }
        __syncthreads();
    }

    #pragma unroll
    for (int mt = 0; mt < 4; ++mt) {
        const int wloc = w0 + wm * 64 + mt * 16 + rowbase;
        #pragma unroll
        for (int nt = 0; nt < 4; ++nt) {
            const int n = wn * 64 + nt * 16 + col;
            if (n >= NTOT_) continue;
            const bool is_off = (n < NOFF_);
            const float bia = is_off ? off_b[n] : msk_b[n - NOFF_];
            union { uint2 u; __half hx[4]; } pk;
            #pragma unroll
            for (int rr = 0; rr < 4; ++rr) {
                float v = acc[mt][nt][rr] + bia;
                if (!is_off) v = 1.f / (1.f + __expf(-v));
                pk.hx[rr] = __float2half(v);
            }
            __half* dst = is_off
                ? (off_o + ((size_t)(b * NOFF_ + n) * H_ + h) * W_ + wloc)
                : (msk_o + ((size_t)(b * NMSK_ + (n - NOFF_)) * H_ + h) * W_ + wloc);
            *(uint2*)dst = pk.u;
        }
    }
}

// ------- kernel 2: bilinear sample + modulated einsum via f16 MFMA --------------
// 3-stage software pipeline: offsets 2 chunks ahead, gathers 1 chunk ahead,
// combine+ds_write just-in-time. All register stages statically named.
struct OffV { float dy, dx, mm; };
struct GathV { half8 c00, c01, c10, c11; float a00, a01, a10, a11; };

__global__ __launch_bounds__(512, 4) void apply_mfma(
    const short* __restrict__ nbf, const __half* __restrict__ off_o,
    const __half* __restrict__ msk_o, const short* __restrict__ Bw3,
    const float* __restrict__ bias, float* __restrict__ out)
{
    __shared__ __align__(16) short As[2][128 * 32];   // 8 KB each

    const int tid  = threadIdx.x;
    const int lane = tid & 63;
    const int wid  = tid >> 6;          // 0..7
    const int col  = lane & 15;
    const int quad = lane >> 4;
    const int wm   = wid & 1;           // px half (64)
    const int wn   = wid >> 1;          // out quarter (16)

    const int bid = blockIdx.x;
    const int wg  = (bid & 7) * 128 + (bid >> 3);   // XCD swizzle, 1024 % 8 == 0
    const int m0  = wg << 7;
    const int b   = m0 >> 16;
    const int h   = (m0 >> 8) & 255;
    const int w0  = m0 & 255;

    const int p     = tid & 127;        // pixel within tile
    const int q     = tid >> 7;         // 0..3: group-slot within chunk
    const int w     = w0 + p;
    const int pix   = h * W_ + w;
    const int slotW = q ^ ((p >> 1) & 3);

    auto loadOffs = [&](int kc) -> OffV {
        const int k = kc >> 1;
        const int g = ((kc & 1) << 2) + q;
        OffV o;
        o.dy = __half2float(off_o[((size_t)(b * NOFF_ + g * 18 + 2 * k)) * HW_ + pix]);
        o.dx = __half2float(off_o[((size_t)(b * NOFF_ + g * 18 + 2 * k + 1)) * HW_ + pix]);
        o.mm = __half2float(msk_o[((size_t)(b * NMSK_ + g * 9 + k)) * HW_ + pix]);
        return o;
    };

    auto issueGather = [&](int kc, OffV o) -> GathV {
        const int k  = kc >> 1;
        const int g  = ((kc & 1) << 2) + q;
        const int ky = k / 3;
        const int kx = k - ky * 3;
        float ys = (float)(h - 1 + ky) + o.dy;
        float xs = (float)(w - 1 + kx) + o.dx;
        float y0f = floorf(ys), x0f = floorf(xs);
        float wy = ys - y0f, wx = xs - x0f;
        int y0 = (int)y0f, x0 = (int)x0f;
        int y1 = y0 + 1, x1 = x0 + 1;
        int yc0 = min(max(y0, 0), H_-1), yc1 = min(max(y1, 0), H_-1);
        float wy0v = (1.f - wy) * (((unsigned)y0 < H_) ? o.mm : 0.f);
        float wy1v = wy * (((unsigned)y1 < H_) ? o.mm : 0.f);
        int xb = min(max(x0, 0), W_-2);
        float wx0v = (((unsigned)x0 < W_) ? (1.f - wx) : 0.f);
        float wx1v = (((unsigned)x1 < W_) ? wx : 0.f);
        float sx0 = (x0 == xb) ? wx0v : ((x1 == xb) ? wx1v : 0.f);
        float sx1 = (x1 == xb + 1) ? wx1v : ((x0 == xb + 1) ? wx0v : 0.f);
        GathV gv;
        gv.a00 = wy0v * sx0; gv.a01 = wy0v * sx1;
        gv.a10 = wy1v * sx0; gv.a11 = wy1v * sx1;
        const short* nb = nbf + (size_t)(b * 8 + g) * HW_ * 8;
        const short* r0 = nb + ((size_t)yc0 * W_ + xb) * 8;
        const short* r1 = nb + ((size_t)yc1 * W_ + xb) * 8;
        gv.c00 = *reinterpret_cast<const half8*>(r0);
        gv.c01 = *reinterpret_cast<const half8*>(r0 + 8);
        gv.c10 = *reinterpret_cast<const half8*>(r1);
        gv.c11 = *reinterpret_cast<const half8*>(r1 + 8);
        return gv;
    };

    auto combineWrite = [&](int kc, const GathV& gv) {
        union { half8 h8; short8 s8; } u;
        #pragma unroll
        for (int c = 0; c < CG_; ++c) {
            float v = gv.a00 * (float)gv.c00[c] + gv.a01 * (float)gv.c01[c]
                    + gv.a10 * (float)gv.c10[c] + gv.a11 * (float)gv.c11[c];
            u.h8[c] = (_Float16)v;
        }
        *reinterpret_cast<short8*>(&As[kc & 1][(p * 4 + slotW) * 8]) = u.s8;
    };

    // per-thread B fragment address (contiguous 1 KB per wave, L1/L2-hot)
    const int nB = wn * 16 + col;
    const short* bPtr = Bw3 + ((nB * 4 + (quad ^ ((nB >> 1) & 3))) << 3);

    f32x4 acc[4];
    #pragma unroll
    for (int mt = 0; mt < 4; ++mt) acc[mt] = f32x4{0.f, 0.f, 0.f, 0.f};

    // prologue: As[0] staged; G = gathers(1); oA = offs(2); oB = offs(3)
    {
        OffV o0 = loadOffs(0);
        GathV g0 = issueGather(0, o0);
        combineWrite(0, g0);
    }
    OffV oA = loadOffs(1);
    GathV G = issueGather(1, oA);
    oA = loadOffs(2);
    OffV oB = loadOffs(3);
    __syncthreads();

    #pragma unroll 1
    for (int kc = 0; kc < 18; ++kc) {
        const int bb = kc & 1;
        const short* AsC = &As[bb][0];

        half8 bv = *reinterpret_cast<const half8*>(bPtr + ((size_t)kc << 11));
        half8 af[4];
        #pragma unroll
        for (int mt = 0; mt < 4; ++mt) {
            const int px = wm * 64 + mt * 16 + col;
            af[mt] = *reinterpret_cast<const half8*>(
                &AsC[(px * 4 + (quad ^ ((px >> 1) & 3))) * 8]);
        }

        if (kc + 1 < 18) combineWrite(kc + 1, G);
        if (kc + 2 < 18) G = issueGather(kc + 2, oA);
        oA = oB;
        if (kc + 4 < 18) oB = loadOffs(kc + 4);

        #pragma unroll
        for (int mt = 0; mt < 4; ++mt)
            acc[mt] = __builtin_amdgcn_mfma_f32_16x16x32_f16(af[mt], bv, acc[mt], 0, 0, 0);

        __syncthreads();
    }

    const int o = wn * 16 + col;
    const float bo = bias[o];
    float* op = out + ((size_t)b * C_ + o) * HW_ + (size_t)h * W_ + w0;
    #pragma unroll
    for (int mt = 0; mt < 4; ++mt) {
        const int px = wm * 64 + mt * 16 + quad * 4;
        float4 st = make_float4(acc[mt][0] + bo, acc[mt][1] + bo,
                                acc[mt][2] + bo, acc[mt][3] + bo);
        *(float4*)(op + px) = st;
    }
}

extern "C" void kernel_launch(void* const* d_in, const int* in_sizes, int n_in,
                              void* d_out, int out_size, void* d_ws, size_t ws_size,
                              hipStream_t stream) {
    const float* ref    = (const float*)d_in[0];
    const float* nbr    = (const float*)d_in[1];
    const float* off_w  = (const float*)d_in[2];
    const float* off_b  = (const float*)d_in[3];
    const float* msk_w  = (const float*)d_in[4];
    const float* msk_b  = (const float*)d_in[5];
    const float* weight = (const float*)d_in[6];
    const float* bias   = (const float*)d_in[7];
    float* out = (float*)d_out;

    // ws carve: off f16 | msk f16 | Bw bf16 | xp (+16KB pad) | Bw3 f16 | nbf f16
    const size_t sz_off = (size_t)B_ * NOFF_ * HW_ * 2;          // 37748736
    const size_t sz_msk = (size_t)B_ * NMSK_ * HW_ * 2;          // 18874368
    const size_t sz_Bw  = (size_t)36 * 256 * 32 * 2;             // 589824
    const size_t sz_xp  = (size_t)B_ * 4 * XPH_ * XPH_ * 32 * 2
                          + 16384;                               // 34097152
    const size_t sz_Bw3 = (size_t)18 * 64 * 32 * 2;              // 73728

    char* ws = (char*)d_ws;
    __half* off_o = (__half*)ws;
    __half* msk_o = (__half*)(ws + sz_off);
    short*  Bw    = (short*)(ws + sz_off + sz_msk);
    short*  xp    = (short*)(ws + sz_off + sz_msk + sz_Bw);
    short*  Bw3   = (short*)(ws + sz_off + sz_msk + sz_Bw + sz_xp);
    short*  nbf   = (short*)(ws + sz_off + sz_msk + sz_Bw + sz_xp + sz_Bw3);

    wtrans2_kernel<<<1152, 256, 0, stream>>>(off_w, msk_w, Bw);
    wtrans3_kernel<<<144, 256, 0, stream>>>(weight, Bw3);
    pack_xp2<<<dim3(B_ * XPH_, 4), 256, 0, stream>>>(ref, nbr, xp, nbf);
    conv_mfma<<<1024, 512, 0, stream>>>(xp, Bw, off_b, msk_b, off_o, msk_o);
    apply_mfma<<<1024, 512, 0, stream>>>(nbf, off_o, msk_o, Bw3, bias, out);
}

// Round 6
// 252.881 us; speedup vs baseline: 2.1800x; 1.0510x over previous
//
#include <hip/hip_runtime.h>
#include <hip/hip_fp16.h>
#include <cstdint>
#include <cstddef>

#define B_ 2
#define C_ 64
#define H_ 256
#define W_ 256
#define HW_ (H_*W_)
#define DG_ 8
#define CG_ 8
#define KK_ 9
#define NOFF_ 144
#define NMSK_ 72
#define NTOT_ 216
#define KRED_ 1152   // 128 * 9
#define XPH_ 258     // padded spatial dim (H+2)

typedef __bf16 bf16x8 __attribute__((ext_vector_type(8)));
typedef _Float16 half8 __attribute__((ext_vector_type(8)));
typedef short  short8 __attribute__((ext_vector_type(8)));
typedef float  f32x4  __attribute__((ext_vector_type(4)));

__device__ __forceinline__ short f2bf(float f) {
    union { float f; uint32_t u; } a; a.f = f;
    uint32_t u = a.u;
    uint32_t r = (u + 0x7fffu + ((u >> 16) & 1u)) >> 16;
    return (short)r;
}

// async global->LDS, 16B per lane: dest = wave-uniform base + lane*16
typedef __attribute__((address_space(1))) const unsigned int g_u32;
typedef __attribute__((address_space(3))) unsigned int l_u32;
__device__ __forceinline__ void gl_lds16(const void* g, void* l) {
    __builtin_amdgcn_global_load_lds((g_u32*)g, (l_u32*)l, 16, 0, 0);
}

// ------ kernel 0b: conv weights -> bf16, step-major, slot-swizzled, 256 rows ----
// Bw[s][n][slot][8ch], s = c4*9 + tap; stored slot = q ^ ((n>>1)&3)
__global__ void wtrans2_kernel(const float* __restrict__ off_w,
                               const float* __restrict__ msk_w,
                               short* __restrict__ Bw) {
    int idx = blockIdx.x * 256 + threadIdx.x;   // 36*256*32 = 294912
    int s    = idx >> 13;          // 8192 shorts per step
    int rem  = idx & 8191;
    int n    = rem >> 5;
    int slot = (rem >> 3) & 3;
    int j    = rem & 7;
    int q    = slot ^ ((n >> 1) & 3);
    int c4   = s / 9;
    int tap  = s - c4 * 9;
    int ch   = c4 * 32 + q * 8 + j;
    float v = 0.f;
    if (n < NOFF_)      v = off_w[(size_t)n * KRED_ + ch * 9 + tap];
    else if (n < NTOT_) v = msk_w[(size_t)(n - NOFF_) * KRED_ + ch * 9 + tap];
    Bw[idx] = f2bf(v);
}

// ------ kernel 0f: apply weights -> f16 chunk-major [18][64][slot4][8] ---------
// kc chunk: k = kc>>1, g = (kc&1)*4 + q, c = j; stored slot = q ^ ((n>>1)&3)
__global__ void wtrans3_kernel(const float* __restrict__ weight,
                               short* __restrict__ Bw3) {
    int idx = blockIdx.x * 256 + threadIdx.x;   // 18*2048 = 36864
    int kc   = idx >> 11;
    int rem  = idx & 2047;
    int n    = rem >> 5;
    int slot = (rem >> 3) & 3;
    int j    = rem & 7;
    int q    = slot ^ ((n >> 1) & 3);
    int k    = kc >> 1;
    int g    = ((kc & 1) << 2) + q;
    int ci   = g * 8 + j;
    union { _Float16 h; short s; } cv;
    cv.h = (_Float16)weight[((size_t)n * 64 + ci) * 9 + k];
    Bw3[idx] = cv.s;
}

// ------- kernel 0e: pack concat(ref,nbr) -> chunk-planar padded bf16 ------------
// xp[b][c4][yi 258][xi 258][slot 4][8ch]; stored slot = q ^ ((xi>>1)&3); zero pad
// fused: for c4>=2 (nbr channels) also emit nbf[b][g][y][x][8ch] f16 (no pad)
__global__ void pack_xp2(const float* __restrict__ ref,
                         const float* __restrict__ nbr,
                         short* __restrict__ xp,
                         short* __restrict__ nbf) {
    const int by = blockIdx.x;          // b*258 + yi
    const int b  = by / XPH_;
    const int yi = by - b * XPH_;
    const int c4 = blockIdx.y;
    const int yg = yi - 1;
    const float* base = (c4 < 2 ? ref : nbr) + ((size_t)b * 64 + (c4 & 1) * 32) * HW_;
    short* rowbase = xp + (((size_t)(b * 4 + c4) * XPH_ + yi) * XPH_) * 32;
    for (int xi = threadIdx.x; xi < XPH_; xi += 256) {
        const int xg = xi - 1;
        const bool valid = ((unsigned)yg < H_) && ((unsigned)xg < W_);
        short* dst = rowbase + (size_t)xi * 32;
        const int sig = (xi >> 1) & 3;
        #pragma unroll
        for (int q = 0; q < 4; ++q) {
            float v[8];
            if (valid) {
                const float* p = base + (size_t)(q * 8) * HW_ + (size_t)yg * W_ + xg;
                #pragma unroll
                for (int j = 0; j < 8; ++j) v[j] = p[(size_t)j * HW_];
            } else {
                #pragma unroll
                for (int j = 0; j < 8; ++j) v[j] = 0.f;
            }
            short8 o;
            #pragma unroll
            for (int j = 0; j < 8; ++j) o[j] = f2bf(v[j]);
            *reinterpret_cast<short8*>(dst + ((q ^ sig) * 8)) = o;
            if (c4 >= 2 && valid) {
                const int g = (c4 - 2) * 4 + q;
                union { half8 h8; short8 s8; } u;
                #pragma unroll
                for (int j = 0; j < 8; ++j) u.h8[j] = (_Float16)v[j];
                *reinterpret_cast<short8*>(
                    nbf + ((size_t)(b * 8 + g) * HW_ + (size_t)yg * W_ + xg) * 8) = u.s8;
            }
        }
    }
}

// ---------------- fused kernel: conv phase -> LDS offmsk -> apply phase ---------
// conv: BM=128 px, BN=256, 8 waves 2Mx4N (round-5 verified structure).
// off/msk tile stays in LDS [216][128] f16, XOR-swizzled (2p ^ ((n&7)<<4)).
// apply: bilinear gather (1-ahead pipeline) + f16 MFMA, offs from LDS.
struct OffV { float dy, dx, mm; };
struct GathV { half8 c00, c01, c10, c11; float a00, a01, a10, a11; };

__global__ __launch_bounds__(512, 4) void fused_conv_apply(
    const short* __restrict__ xp, const short* __restrict__ Bw,
    const float* __restrict__ off_b, const float* __restrict__ msk_b,
    const short* __restrict__ nbf, const short* __restrict__ Bw3,
    const float* __restrict__ bias, float* __restrict__ out)
{
    __shared__ __align__(16) short AsBuf[2][4608];        // conv 9KB/buf; apply reuses 8KB
    __shared__ __align__(16) short offmsk[NTOT_ * 128];   // 55296 B

    const int tid  = threadIdx.x;
    const int lane = tid & 63;
    const int wid  = tid >> 6;          // 0..7
    const int wm   = wid & 1;           // px half (64)
    const int wn   = wid >> 1;          // n quarter (64)
    const int col     = lane & 15;
    const int quad    = lane >> 4;
    const int rowbase = quad * 4;

    // XCD-aware bijective swizzle (1024 blocks % 8 == 0)
    const int bid = blockIdx.x;
    const int wg  = (bid & 7) * 128 + (bid >> 3);
    const int m0 = wg << 7;
    const int b  = m0 >> 16;
    const int h  = (m0 >> 8) & 255;
    const int w0 = m0 & 255;

    // ============================ conv phase ====================================
    {
        int bOff[4];
        #pragma unroll
        for (int nt = 0; nt < 4; ++nt) {
            int n = wn * 64 + nt * 16 + col;
            bOff[nt] = (n * 4 + (quad ^ ((n >> 1) & 3))) * 8;
        }
        int pxv[4];
        #pragma unroll
        for (int mt = 0; mt < 4; ++mt) pxv[mt] = wm * 64 + mt * 16 + col;

        f32x4 acc[4][4];
        #pragma unroll
        for (int i = 0; i < 4; ++i)
            #pragma unroll
            for (int j = 0; j < 4; ++j) acc[i][j] = f32x4{0.f, 0.f, 0.f, 0.f};

        auto stageA = [&](int win, int bb) {
            const int c4s = win / 3;
            const int dys = win - c4s * 3;
            const short* sA = xp + (((size_t)(b * 4 + c4s) * XPH_ + (h + dys)) * XPH_
                                    + w0) * 32;
            char* dA = (char*)&AsBuf[bb][0];
            gl_lds16(sA + (size_t)tid * 8, dA + wid * 1024);
            if (tid < 32) gl_lds16(sA + (size_t)(512 + tid) * 8, dA + 8192);
        };

        stageA(0, 0);
        __syncthreads();

        #pragma unroll 1
        for (int win = 0; win < 12; ++win) {
            const int bb = win & 1;
            if (win < 11) stageA(win + 1, bb ^ 1);
            const short* AsC = &AsBuf[bb][0];

            #pragma unroll
            for (int dx = 0; dx < 3; ++dx) {
                const int s = win * 3 + dx;
                const short* bp = Bw + ((size_t)s << 13);

                bf16x8 bv[4];
                #pragma unroll
                for (int nt = 0; nt < 4; ++nt)
                    bv[nt] = *reinterpret_cast<const bf16x8*>(bp + bOff[nt]);

                bf16x8 af[4];
                #pragma unroll
                for (int mt = 0; mt < 4; ++mt) {
                    const int px = pxv[mt] + dx;
                    af[mt] = *reinterpret_cast<const bf16x8*>(
                        &AsC[(px * 4 + (quad ^ ((px >> 1) & 3))) * 8]);
                }

                #pragma unroll
                for (int mt = 0; mt < 4; ++mt)
                    #pragma unroll
                    for (int nt = 0; nt < 4; ++nt)
                        acc[mt][nt] = __builtin_amdgcn_mfma_f32_16x16x32_bf16(
                            af[mt], bv[nt], acc[mt][nt], 0, 0, 0);
            }
            __syncthreads();
        }

        // epilogue: bias (+sigmoid for mask rows) -> LDS offmsk, XOR-swizzled
        #pragma unroll
        for (int mt = 0; mt < 4; ++mt) {
            const int p4 = wm * 64 + mt * 16 + rowbase;
            #pragma unroll
            for (int nt = 0; nt < 4; ++nt) {
                const int n = wn * 64 + nt * 16 + col;
                if (n >= NTOT_) continue;
                const bool is_off = (n < NOFF_);
                const float bia = is_off ? off_b[n] : msk_b[n - NOFF_];
                union { uint2 u; __half hx[4]; } pk;
                #pragma unroll
                for (int rr = 0; rr < 4; ++rr) {
                    float v = acc[mt][nt][rr] + bia;
                    if (!is_off) v = 1.f / (1.f + __expf(-v));
                    pk.hx[rr] = __float2half(v);
                }
                const int byt = n * 256 + ((2 * p4) ^ ((n & 7) << 4));
                *(uint2*)((char*)offmsk + byt) = pk.u;
            }
        }
    }
    __syncthreads();   // offmsk visible; conv As reads all complete

    // ============================ apply phase ===================================
    {
        const int p     = tid & 127;        // pixel within tile
        const int q     = tid >> 7;         // 0..3: group-slot within chunk
        const int w     = w0 + p;
        const int slotW = q ^ ((p >> 1) & 3);

        auto ldsOff = [&](int n, int pp) -> float {
            const int byt = n * 256 + ((2 * pp) ^ ((n & 7) << 4));
            return __half2float(*reinterpret_cast<const __half*>(
                (const char*)offmsk + byt));
        };
        auto loadOffs = [&](int kc) -> OffV {
            const int k = kc >> 1;
            const int g = ((kc & 1) << 2) + q;
            OffV o;
            o.dy = ldsOff(g * 18 + 2 * k,     p);
            o.dx = ldsOff(g * 18 + 2 * k + 1, p);
            o.mm = ldsOff(NOFF_ + g * 9 + k,  p);
            return o;
        };

        auto issueGather = [&](int kc, OffV o) -> GathV {
            const int k  = kc >> 1;
            const int g  = ((kc & 1) << 2) + q;
            const int ky = k / 3;
            const int kx = k - ky * 3;
            float ys = (float)(h - 1 + ky) + o.dy;
            float xs = (float)(w - 1 + kx) + o.dx;
            float y0f = floorf(ys), x0f = floorf(xs);
            float wy = ys - y0f, wx = xs - x0f;
            int y0 = (int)y0f, x0 = (int)x0f;
            int y1 = y0 + 1, x1 = x0 + 1;
            int yc0 = min(max(y0, 0), H_-1), yc1 = min(max(y1, 0), H_-1);
            float wy0v = (1.f - wy) * (((unsigned)y0 < H_) ? o.mm : 0.f);
            float wy1v = wy * (((unsigned)y1 < H_) ? o.mm : 0.f);
            int xb = min(max(x0, 0), W_-2);
            float wx0v = (((unsigned)x0 < W_) ? (1.f - wx) : 0.f);
            float wx1v = (((unsigned)x1 < W_) ? wx : 0.f);
            float sx0 = (x0 == xb) ? wx0v : ((x1 == xb) ? wx1v : 0.f);
            float sx1 = (x1 == xb + 1) ? wx1v : ((x0 == xb + 1) ? wx0v : 0.f);
            GathV gv;
            gv.a00 = wy0v * sx0; gv.a01 = wy0v * sx1;
            gv.a10 = wy1v * sx0; gv.a11 = wy1v * sx1;
            const short* nb = nbf + (size_t)(b * 8 + g) * HW_ * 8;
            const short* r0 = nb + ((size_t)yc0 * W_ + xb) * 8;
            const short* r1 = nb + ((size_t)yc1 * W_ + xb) * 8;
            gv.c00 = *reinterpret_cast<const half8*>(r0);
            gv.c01 = *reinterpret_cast<const half8*>(r0 + 8);
            gv.c10 = *reinterpret_cast<const half8*>(r1);
            gv.c11 = *reinterpret_cast<const half8*>(r1 + 8);
            return gv;
        };

        auto combineWrite = [&](int kc, const GathV& gv) {
            union { half8 h8; short8 s8; } u;
            #pragma unroll
            for (int c = 0; c < CG_; ++c) {
                float v = gv.a00 * (float)gv.c00[c] + gv.a01 * (float)gv.c01[c]
                        + gv.a10 * (float)gv.c10[c] + gv.a11 * (float)gv.c11[c];
                u.h8[c] = (_Float16)v;
            }
            *reinterpret_cast<short8*>(&AsBuf[kc & 1][(p * 4 + slotW) * 8]) = u.s8;
        };

        // per-thread B fragment address (contiguous 1 KB per wave, L1/L2-hot)
        const int nB = wn * 16 + col;
        const short* bPtr = Bw3 + ((nB * 4 + (quad ^ ((nB >> 1) & 3))) << 3);

        f32x4 acc2[4];
        #pragma unroll
        for (int mt = 0; mt < 4; ++mt) acc2[mt] = f32x4{0.f, 0.f, 0.f, 0.f};

        {
            OffV o0 = loadOffs(0);
            GathV g0 = issueGather(0, o0);
            combineWrite(0, g0);
        }
        GathV G = issueGather(1, loadOffs(1));
        __syncthreads();

        #pragma unroll 1
        for (int kc = 0; kc < 18; ++kc) {
            const int bb = kc & 1;
            const short* AsC = &AsBuf[bb][0];

            half8 bv = *reinterpret_cast<const half8*>(bPtr + ((size_t)kc << 11));
            half8 af[4];
            #pragma unroll
            for (int mt = 0; mt < 4; ++mt) {
                const int px = wm * 64 + mt * 16 + col;
                af[mt] = *reinterpret_cast<const half8*>(
                    &AsC[(px * 4 + (quad ^ ((px >> 1) & 3))) * 8]);
            }

            if (kc + 1 < 18) combineWrite(kc + 1, G);
            if (kc + 2 < 18) G = issueGather(kc + 2, loadOffs(kc + 2));

            #pragma unroll
            for (int mt = 0; mt < 4; ++mt)
                acc2[mt] = __builtin_amdgcn_mfma_f32_16x16x32_f16(af[mt], bv, acc2[mt], 0, 0, 0);

            __syncthreads();
        }

        const int o = wn * 16 + col;
        const float bo = bias[o];
        float* op = out + ((size_t)b * C_ + o) * HW_ + (size_t)h * W_ + w0;
        #pragma unroll
        for (int mt = 0; mt < 4; ++mt) {
            const int px = wm * 64 + mt * 16 + quad * 4;
            float4 st = make_float4(acc2[mt][0] + bo, acc2[mt][1] + bo,
                                    acc2[mt][2] + bo, acc2[mt][3] + bo);
            *(float4*)(op + px) = st;
        }
    }
}

extern "C" void kernel_launch(void* const* d_in, const int* in_sizes, int n_in,
                              void* d_out, int out_size, void* d_ws, size_t ws_size,
                              hipStream_t stream) {
    const float* ref    = (const float*)d_in[0];
    const float* nbr    = (const float*)d_in[1];
    const float* off_w  = (const float*)d_in[2];
    const float* off_b  = (const float*)d_in[3];
    const float* msk_w  = (const float*)d_in[4];
    const float* msk_b  = (const float*)d_in[5];
    const float* weight = (const float*)d_in[6];
    const float* bias   = (const float*)d_in[7];
    float* out = (float*)d_out;

    // ws carve: Bw bf16 | xp (+16KB pad) | Bw3 f16 | nbf f16
    const size_t sz_Bw  = (size_t)36 * 256 * 32 * 2;             // 589824
    const size_t sz_xp  = (size_t)B_ * 4 * XPH_ * XPH_ * 32 * 2
                          + 16384;                               // 34097152
    const size_t sz_Bw3 = (size_t)18 * 64 * 32 * 2;              // 73728

    char* ws = (char*)d_ws;
    short* Bw  = (short*)ws;
    short* xp  = (short*)(ws + sz_Bw);
    short* Bw3 = (short*)(ws + sz_Bw + sz_xp);
    short* nbf = (short*)(ws + sz_Bw + sz_xp + sz_Bw3);

    wtrans2_kernel<<<1152, 256, 0, stream>>>(off_w, msk_w, Bw);
    wtrans3_kernel<<<144, 256, 0, stream>>>(weight, Bw3);
    pack_xp2<<<dim3(B_ * XPH_, 4), 256, 0, stream>>>(ref, nbr, xp, nbf);
    fused_conv_apply<<<1024, 512, 0, stream>>>(xp, Bw, off_b, msk_b,
                                               nbf, Bw3, bias, out);
}

// Round 7
// 248.201 us; speedup vs baseline: 2.2211x; 1.0189x over previous
//
#include <hip/hip_runtime.h>
#include <hip/hip_fp16.h>
#include <cstdint>
#include <cstddef>

#define B_ 2
#define C_ 64
#define H_ 256
#define W_ 256
#define HW_ (H_*W_)
#define DG_ 8
#define CG_ 8
#define KK_ 9
#define NOFF_ 144
#define NMSK_ 72
#define NTOT_ 216
#define KRED_ 1152   // 128 * 9
#define XPH_ 258     // padded spatial dim (H+2)

typedef __bf16 bf16x8 __attribute__((ext_vector_type(8)));
typedef _Float16 half8 __attribute__((ext_vector_type(8)));
typedef short  short8 __attribute__((ext_vector_type(8)));
typedef float  f32x4  __attribute__((ext_vector_type(4)));

__device__ __forceinline__ short f2bf(float f) {
    union { float f; uint32_t u; } a; a.f = f;
    uint32_t u = a.u;
    uint32_t r = (u + 0x7fffu + ((u >> 16) & 1u)) >> 16;
    return (short)r;
}

// async global->LDS, 16B per lane: dest = wave-uniform base + lane*16
typedef __attribute__((address_space(1))) const unsigned int g_u32;
typedef __attribute__((address_space(3))) unsigned int l_u32;
__device__ __forceinline__ void gl_lds16(const void* g, void* l) {
    __builtin_amdgcn_global_load_lds((g_u32*)g, (l_u32*)l, 16, 0, 0);
}

// ---------------- prep: pack + both weight transposes in ONE launch -------------
// blocks [0,2064): pack concat(ref,nbr) -> chunk-planar padded bf16 xp + nbf f16
// blocks [2064,3216): conv weights -> bf16 step-major slot-swizzled Bw
// blocks [3216,3360): apply weights -> f16 chunk-major Bw3
__global__ __launch_bounds__(256) void prep_all(
    const float* __restrict__ ref, const float* __restrict__ nbr,
    const float* __restrict__ off_w, const float* __restrict__ msk_w,
    const float* __restrict__ weight,
    short* __restrict__ xp, short* __restrict__ nbf,
    short* __restrict__ Bw, short* __restrict__ Bw3)
{
    const int bid = blockIdx.x;
    const int tid = threadIdx.x;

    if (bid < 2064) {
        // ---- pack part: xp[b][c4][yi][xi][slot4][8], slot = q ^ ((xi>>1)&3) ----
        const int by = bid >> 2;            // b*258 + yi
        const int c4 = bid & 3;
        const int b  = by / XPH_;
        const int yi = by - b * XPH_;
        const int yg = yi - 1;
        const float* base = (c4 < 2 ? ref : nbr)
                            + ((size_t)b * 64 + (c4 & 1) * 32) * HW_;
        short* rowbase = xp + (((size_t)(b * 4 + c4) * XPH_ + yi) * XPH_) * 32;
        for (int xi = tid; xi < XPH_; xi += 256) {
            const int xg = xi - 1;
            const bool valid = ((unsigned)yg < H_) && ((unsigned)xg < W_);
            short* dst = rowbase + (size_t)xi * 32;
            const int sig = (xi >> 1) & 3;
            #pragma unroll
            for (int q = 0; q < 4; ++q) {
                float v[8];
                if (valid) {
                    const float* p = base + (size_t)(q * 8) * HW_
                                     + (size_t)yg * W_ + xg;
                    #pragma unroll
                    for (int j = 0; j < 8; ++j) v[j] = p[(size_t)j * HW_];
                } else {
                    #pragma unroll
                    for (int j = 0; j < 8; ++j) v[j] = 0.f;
                }
                short8 o;
                #pragma unroll
                for (int j = 0; j < 8; ++j) o[j] = f2bf(v[j]);
                *reinterpret_cast<short8*>(dst + ((q ^ sig) * 8)) = o;
                if (c4 >= 2 && valid) {
                    const int g = (c4 - 2) * 4 + q;
                    union { half8 h8; short8 s8; } u;
                    #pragma unroll
                    for (int j = 0; j < 8; ++j) u.h8[j] = (_Float16)v[j];
                    *reinterpret_cast<short8*>(
                        nbf + ((size_t)(b * 8 + g) * HW_
                               + (size_t)yg * W_ + xg) * 8) = u.s8;
                }
            }
        }
    } else if (bid < 3216) {
        // ---- conv weights: Bw[s][n][slot][8ch], s = c4*9 + tap ----
        int idx = (bid - 2064) * 256 + tid;   // 36*256*32 = 294912
        int s    = idx >> 13;
        int rem  = idx & 8191;
        int n    = rem >> 5;
        int slot = (rem >> 3) & 3;
        int j    = rem & 7;
        int q    = slot ^ ((n >> 1) & 3);
        int c4   = s / 9;
        int tap  = s - c4 * 9;
        int ch   = c4 * 32 + q * 8 + j;
        float v = 0.f;
        if (n < NOFF_)      v = off_w[(size_t)n * KRED_ + ch * 9 + tap];
        else if (n < NTOT_) v = msk_w[(size_t)(n - NOFF_) * KRED_ + ch * 9 + tap];
        Bw[idx] = f2bf(v);
    } else {
        // ---- apply weights: Bw3[18][64][slot4][8] f16 ----
        int idx = (bid - 3216) * 256 + tid;   // 18*2048 = 36864
        int kc   = idx >> 11;
        int rem  = idx & 2047;
        int n    = rem >> 5;
        int slot = (rem >> 3) & 3;
        int j    = rem & 7;
        int q    = slot ^ ((n >> 1) & 3);
        int k    = kc >> 1;
        int g    = ((kc & 1) << 2) + q;
        int ci   = g * 8 + j;
        union { _Float16 h; short s; } cv;
        cv.h = (_Float16)weight[((size_t)n * 64 + ci) * 9 + k];
        Bw3[idx] = cv.s;
    }
}

// ---------------- fused kernel: conv phase -> LDS offmsk -> apply phase ---------
struct OffV { float dy, dx, mm; };
struct GathV { half8 c00, c01, c10, c11; float a00, a01, a10, a11; };

__global__ __launch_bounds__(512, 4) void fused_conv_apply(
    const short* __restrict__ xp, const short* __restrict__ Bw,
    const float* __restrict__ off_b, const float* __restrict__ msk_b,
    const short* __restrict__ nbf, const short* __restrict__ Bw3,
    const float* __restrict__ bias, float* __restrict__ out)
{
    __shared__ __align__(16) short AsBuf[2][4608];        // conv 9KB/buf; apply reuses 8KB
    __shared__ __align__(16) short offmsk[NTOT_ * 128];   // 55296 B

    const int tid  = threadIdx.x;
    const int lane = tid & 63;
    const int wid  = tid >> 6;          // 0..7
    const int wm   = wid & 1;           // px half (64)
    const int wn   = wid >> 1;          // n quarter (64)
    const int col     = lane & 15;
    const int quad    = lane >> 4;
    const int rowbase = quad * 4;

    // XCD-aware bijective swizzle (1024 blocks % 8 == 0)
    const int bid = blockIdx.x;
    const int wg  = (bid & 7) * 128 + (bid >> 3);
    const int m0 = wg << 7;
    const int b  = m0 >> 16;
    const int h  = (m0 >> 8) & 255;
    const int w0 = m0 & 255;

    // ============================ conv phase ====================================
    {
        int bOff[4];
        #pragma unroll
        for (int nt = 0; nt < 4; ++nt) {
            int n = wn * 64 + nt * 16 + col;
            bOff[nt] = (n * 4 + (quad ^ ((n >> 1) & 3))) * 8;
        }
        int pxv[4];
        #pragma unroll
        for (int mt = 0; mt < 4; ++mt) pxv[mt] = wm * 64 + mt * 16 + col;

        f32x4 acc[4][4];
        #pragma unroll
        for (int i = 0; i < 4; ++i)
            #pragma unroll
            for (int j = 0; j < 4; ++j) acc[i][j] = f32x4{0.f, 0.f, 0.f, 0.f};

        auto stageA = [&](int win, int bb) {
            const int c4s = win / 3;
            const int dys = win - c4s * 3;
            const short* sA = xp + (((size_t)(b * 4 + c4s) * XPH_ + (h + dys)) * XPH_
                                    + w0) * 32;
            char* dA = (char*)&AsBuf[bb][0];
            gl_lds16(sA + (size_t)tid * 8, dA + wid * 1024);
            if (tid < 32) gl_lds16(sA + (size_t)(512 + tid) * 8, dA + 8192);
        };

        stageA(0, 0);
        __syncthreads();

        #pragma unroll 1
        for (int win = 0; win < 12; ++win) {
            const int bb = win & 1;
            if (win < 11) stageA(win + 1, bb ^ 1);
            const short* AsC = &AsBuf[bb][0];

            #pragma unroll
            for (int dx = 0; dx < 3; ++dx) {
                const int s = win * 3 + dx;
                const short* bp = Bw + ((size_t)s << 13);

                bf16x8 bv[4];
                #pragma unroll
                for (int nt = 0; nt < 4; ++nt)
                    bv[nt] = *reinterpret_cast<const bf16x8*>(bp + bOff[nt]);

                bf16x8 af[4];
                #pragma unroll
                for (int mt = 0; mt < 4; ++mt) {
                    const int px = pxv[mt] + dx;
                    af[mt] = *reinterpret_cast<const bf16x8*>(
                        &AsC[(px * 4 + (quad ^ ((px >> 1) & 3))) * 8]);
                }

                __builtin_amdgcn_s_setprio(1);
                #pragma unroll
                for (int mt = 0; mt < 4; ++mt)
                    #pragma unroll
                    for (int nt = 0; nt < 4; ++nt)
                        acc[mt][nt] = __builtin_amdgcn_mfma_f32_16x16x32_bf16(
                            af[mt], bv[nt], acc[mt][nt], 0, 0, 0);
                __builtin_amdgcn_s_setprio(0);
            }
            __syncthreads();
        }

        // epilogue: bias (+sigmoid for mask rows) -> LDS offmsk, XOR-swizzled
        #pragma unroll
        for (int mt = 0; mt < 4; ++mt) {
            const int p4 = wm * 64 + mt * 16 + rowbase;
            #pragma unroll
            for (int nt = 0; nt < 4; ++nt) {
                const int n = wn * 64 + nt * 16 + col;
                if (n >= NTOT_) continue;
                const bool is_off = (n < NOFF_);
                const float bia = is_off ? off_b[n] : msk_b[n - NOFF_];
                union { uint2 u; __half hx[4]; } pk;
                #pragma unroll
                for (int rr = 0; rr < 4; ++rr) {
                    float v = acc[mt][nt][rr] + bia;
                    if (!is_off) v = 1.f / (1.f + __expf(-v));
                    pk.hx[rr] = __float2half(v);
                }
                const int byt = n * 256 + ((2 * p4) ^ ((n & 7) << 4));
                *(uint2*)((char*)offmsk + byt) = pk.u;
            }
        }
    }
    __syncthreads();   // offmsk visible; conv As reads all complete

    // ============================ apply phase ===================================
    {
        const int p     = tid & 127;        // pixel within tile
        const int q     = tid >> 7;         // 0..3: group-slot within chunk
        const int w     = w0 + p;
        const int slotW = q ^ ((p >> 1) & 3);

        auto ldsOff = [&](int n, int pp) -> float {
            const int byt = n * 256 + ((2 * pp) ^ ((n & 7) << 4));
            return __half2float(*reinterpret_cast<const __half*>(
                (const char*)offmsk + byt));
        };
        auto loadOffs = [&](int kc) -> OffV {
            const int k = kc >> 1;
            const int g = ((kc & 1) << 2) + q;
            OffV o;
            o.dy = ldsOff(g * 18 + 2 * k,     p);
            o.dx = ldsOff(g * 18 + 2 * k + 1, p);
            o.mm = ldsOff(NOFF_ + g * 9 + k,  p);
            return o;
        };

        auto issueGather = [&](int kc, OffV o) -> GathV {
            const int k  = kc >> 1;
            const int g  = ((kc & 1) << 2) + q;
            const int ky = k / 3;
            const int kx = k - ky * 3;
            float ys = (float)(h - 1 + ky) + o.dy;
            float xs = (float)(w - 1 + kx) + o.dx;
            float y0f = floorf(ys), x0f = floorf(xs);
            float wy = ys - y0f, wx = xs - x0f;
            int y0 = (int)y0f, x0 = (int)x0f;
            int y1 = y0 + 1, x1 = x0 + 1;
            int yc0 = min(max(y0, 0), H_-1), yc1 = min(max(y1, 0), H_-1);
            float wy0v = (1.f - wy) * (((unsigned)y0 < H_) ? o.mm : 0.f);
            float wy1v = wy * (((unsigned)y1 < H_) ? o.mm : 0.f);
            int xb = min(max(x0, 0), W_-2);
            float wx0v = (((unsigned)x0 < W_) ? (1.f - wx) : 0.f);
            float wx1v = (((unsigned)x1 < W_) ? wx : 0.f);
            float sx0 = (x0 == xb) ? wx0v : ((x1 == xb) ? wx1v : 0.f);
            float sx1 = (x1 == xb + 1) ? wx1v : ((x0 == xb + 1) ? wx0v : 0.f);
            GathV gv;
            gv.a00 = wy0v * sx0; gv.a01 = wy0v * sx1;
            gv.a10 = wy1v * sx0; gv.a11 = wy1v * sx1;
            const short* nb = nbf + (size_t)(b * 8 + g) * HW_ * 8;
            const short* r0 = nb + ((size_t)yc0 * W_ + xb) * 8;
            const short* r1 = nb + ((size_t)yc1 * W_ + xb) * 8;
            gv.c00 = *reinterpret_cast<const half8*>(r0);
            gv.c01 = *reinterpret_cast<const half8*>(r0 + 8);
            gv.c10 = *reinterpret_cast<const half8*>(r1);
            gv.c11 = *reinterpret_cast<const half8*>(r1 + 8);
            return gv;
        };

        auto combineWrite = [&](int kc, const GathV& gv) {
            union { half8 h8; short8 s8; } u;
            #pragma unroll
            for (int c = 0; c < CG_; ++c) {
                float v = gv.a00 * (float)gv.c00[c] + gv.a01 * (float)gv.c01[c]
                        + gv.a10 * (float)gv.c10[c] + gv.a11 * (float)gv.c11[c];
                u.h8[c] = (_Float16)v;
            }
            *reinterpret_cast<short8*>(&AsBuf[kc & 1][(p * 4 + slotW) * 8]) = u.s8;
        };

        // per-thread B fragment address (contiguous 1 KB per wave, L1/L2-hot)
        const int nB = wn * 16 + col;
        const short* bPtr = Bw3 + ((nB * 4 + (quad ^ ((nB >> 1) & 3))) << 3);

        f32x4 acc2[4];
        #pragma unroll
        for (int mt = 0; mt < 4; ++mt) acc2[mt] = f32x4{0.f, 0.f, 0.f, 0.f};

        // 2-ahead gather pipeline, static GA/GB roles (no runtime-indexed regs)
        {
            OffV o0 = loadOffs(0);
            GathV g0 = issueGather(0, o0);
            combineWrite(0, g0);
        }
        GathV GA = issueGather(1, loadOffs(1));   // for kc=1
        GathV GB = issueGather(2, loadOffs(2));   // for kc=2
        __syncthreads();

        auto bodyKC = [&](int kc, GathV& Gcur, GathV& Gnext) {
            const short* AsC = &AsBuf[kc & 1][0];

            half8 bv = *reinterpret_cast<const half8*>(bPtr + ((size_t)kc << 11));
            half8 af[4];
            #pragma unroll
            for (int mt = 0; mt < 4; ++mt) {
                const int px = wm * 64 + mt * 16 + col;
                af[mt] = *reinterpret_cast<const half8*>(
                    &AsC[(px * 4 + (quad ^ ((px >> 1) & 3))) * 8]);
            }

            if (kc + 1 < 18) combineWrite(kc + 1, Gcur);
            if (kc + 3 < 18) Gcur = issueGather(kc + 3, loadOffs(kc + 3));

            __builtin_amdgcn_s_setprio(1);
            #pragma unroll
            for (int mt = 0; mt < 4; ++mt)
                acc2[mt] = __builtin_amdgcn_mfma_f32_16x16x32_f16(
                    af[mt], bv, acc2[mt], 0, 0, 0);
            __builtin_amdgcn_s_setprio(0);
            __syncthreads();
            (void)Gnext;
        };

        #pragma unroll 1
        for (int kc2 = 0; kc2 < 18; kc2 += 2) {
            bodyKC(kc2,     GA, GB);
            bodyKC(kc2 + 1, GB, GA);
        }

        const int o = wn * 16 + col;
        const float bo = bias[o];
        float* op = out + ((size_t)b * C_ + o) * HW_ + (size_t)h * W_ + w0;
        #pragma unroll
        for (int mt = 0; mt < 4; ++mt) {
            const int px = wm * 64 + mt * 16 + quad * 4;
            float4 st = make_float4(acc2[mt][0] + bo, acc2[mt][1] + bo,
                                    acc2[mt][2] + bo, acc2[mt][3] + bo);
            *(float4*)(op + px) = st;
        }
    }
}

extern "C" void kernel_launch(void* const* d_in, const int* in_sizes, int n_in,
                              void* d_out, int out_size, void* d_ws, size_t ws_size,
                              hipStream_t stream) {
    const float* ref    = (const float*)d_in[0];
    const float* nbr    = (const float*)d_in[1];
    const float* off_w  = (const float*)d_in[2];
    const float* off_b  = (const float*)d_in[3];
    const float* msk_w  = (const float*)d_in[4];
    const float* msk_b  = (const float*)d_in[5];
    const float* weight = (const float*)d_in[6];
    const float* bias   = (const float*)d_in[7];
    float* out = (float*)d_out;

    // ws carve: Bw bf16 | xp (+16KB pad) | Bw3 f16 | nbf f16
    const size_t sz_Bw  = (size_t)36 * 256 * 32 * 2;             // 589824
    const size_t sz_xp  = (size_t)B_ * 4 * XPH_ * XPH_ * 32 * 2
                          + 16384;                               // 34097152
    const size_t sz_Bw3 = (size_t)18 * 64 * 32 * 2;              // 73728

    char* ws = (char*)d_ws;
    short* Bw  = (short*)ws;
    short* xp  = (short*)(ws + sz_Bw);
    short* Bw3 = (short*)(ws + sz_Bw + sz_xp);
    short* nbf = (short*)(ws + sz_Bw + sz_xp + sz_Bw3);

    prep_all<<<3360, 256, 0, stream>>>(ref, nbr, off_w, msk_w, weight,
                                       xp, nbf, Bw, Bw3);
    fused_conv_apply<<<1024, 512, 0, stream>>>(xp, Bw, off_b, msk_b,
                                               nbf, Bw3, bias, out);
}